// Round 14
// baseline (2295.428 us; speedup 1.0000x reference)
//
#include <hip/hip_runtime.h>
#include <stdint.h>

// ---------------------------------------------------------------------------
// Encoder (GAT + 2x GRU + link/gen heads), MI355X. FP32 I/O, bf16 MFMA inside.
// R12: revert R11's persistent GRU (FETCH 4.2GB, L2-thrash, 2.3x regression).
// Back to R10 structure; single change: k_gru_step6 with BM=32 (LDS 66->33KB,
// 2->4 blocks/CU, grid 1024->2048) for latency hiding + tail parallelism.
// ---------------------------------------------------------------------------

typedef __attribute__((ext_vector_type(8))) short bf16x8;
typedef __attribute__((ext_vector_type(4))) float f32x4;

#define PADW 8

__device__ __forceinline__ unsigned short f2b(float f) {
    union { float f; unsigned int u; } v; v.f = f;
    return (unsigned short)((v.u + 0x7fffu + ((v.u >> 16) & 1u)) >> 16);
}
__device__ __forceinline__ float b2f(unsigned short b) {
    union { unsigned int u; float f; } v; v.u = ((unsigned int)b) << 16;
    return v.f;
}

// ---- prep: Wat[n=h*128+d][k] = bf16(W_att[h][k][d])
__global__ void k_prep_wat(const float* watt, unsigned short* dst) {
    int idx = blockIdx.x * 256 + threadIdx.x;
    if (idx >= 512 * 512) return;
    int n = idx >> 9, k = idx & 511;
    int h = n >> 7, d = n & 127;
    dst[idx] = f2b(watt[(h * 512 + k) * 128 + d]);
}

// ---- prep: lgT[s][n][k] = bf16((s?genW:linkW)[k][n])
__global__ void k_prep_lg(const float* linkW, const float* genW,
                          unsigned short* dst) {
    int idx = blockIdx.x * 256 + threadIdx.x;
    if (idx >= 2 * 512 * 1024) return;
    int s = idx >> 19;
    int o = idx & 524287;
    int n = o >> 10, k = o & 1023;
    const float* W = s ? genW : linkW;
    dst[idx] = f2b(W[k * 512 + n]);
}

// ---- prep: wz = bf16 copies of [gi_Wi, gi_Wh, go_Wi, go_Wh], each 1536x512
__global__ void k_prep_gruw(const float* a, const float* b, const float* c,
                            const float* d, unsigned short* dst) {
    int idx = blockIdx.x * 256 + threadIdx.x;
    if (idx >= 4 * 786432) return;
    int s = idx / 786432, o = idx % 786432;
    const float* src = (s == 0) ? a : (s == 1) ? b : (s == 2) ? c : d;
    dst[idx] = f2b(src[o]);
}

// ---- prep: Wh in MFMA-fragment order
__global__ void k_prep_whfrag(const float* wh_in, const float* wh_out,
                              unsigned short* dst) {
    int idx = blockIdx.x * 256 + threadIdx.x;
    if (idx >= 2 * 786432) return;
    int g = idx / 786432;
    int r2 = idx % 786432;
    int q = r2 / 262144;
    int r3 = r2 % 262144;
    int nb = r3 >> 15;
    int wn = (r3 >> 14) & 1;
    int nf = (r3 >> 13) & 1;
    int kt = (r3 >> 9) & 15;
    int lane = (r3 >> 3) & 63;
    int e = r3 & 7;
    int row = q * 512 + nb * 64 + wn * 32 + nf * 16 + (lane & 15);
    int col = kt * 32 + (lane >> 4) * 8 + e;
    const float* src = g ? wh_out : wh_in;
    dst[idx] = f2b(src[row * 512 + col]);
}

// ---- prep: bf16 copy of word_emb (tier A)
__global__ void k_prep_wemb(const float* we, unsigned short* dst) {
    int idx = blockIdx.x * 256 + threadIdx.x;
    if (idx >= 2048000) return;
    const float* s = we + (size_t)idx * 8;
    float4 a = ((const float4*)s)[0], b = ((const float4*)s)[1];
    alignas(16) unsigned short t8[8] = {
        f2b(a.x), f2b(a.y), f2b(a.z), f2b(a.w),
        f2b(b.x), f2b(b.y), f2b(b.z), f2b(b.w)};
    *(uint4*)&dst[(size_t)idx * 8] = *(uint4*)t8;
}

// ---- bitpack adjacency
__global__ void k_bitpack(const int* inner, const int* outer, unsigned long long* bits) {
    int row = blockIdx.x * 4 + (threadIdx.x >> 6);
    int lane = threadIdx.x & 63;
    int g = row >> 12, i = row & 4095;
    const int* adj = (g ? outer : inner) + (size_t)i * 4096;
    unsigned long long* d = bits + (size_t)row * 64;
    for (int w = 0; w < 64; w++) {
        int v = adj[w * 64 + lane];
        unsigned long long m = __ballot(v != 0);
        if (lane == 0) d[w] = m;
    }
}

// ---- zero h state
__global__ void k_zero(float* hf, unsigned short* hb0) {
    int idx = blockIdx.x * 256 + threadIdx.x;
    if (idx < 8192 * 512) { hf[idx] = 0.f; hb0[idx] = 0; }
}

// ---- stable counting sort by len (descending), per half
__global__ void k_sort(const int* in_len, const int* out_len,
                       int* perm, int* slen, int* ipos) {
    int bid = blockIdx.x;
    int half = bid >> 6;
    int v = 64 - (bid & 63);
    const int* len = half ? out_len : in_len;
    int lane = threadIdx.x;
    int base = 0;
    for (int i0 = 0; i0 < 4096; i0 += 64) {
        unsigned long long m = __ballot(len[i0 + lane] > v);
        base += __popcll(m);
    }
    int off = 0;
    for (int i0 = 0; i0 < 4096; i0 += 64) {
        int l = len[i0 + lane];
        unsigned long long m = __ballot(l == v);
        int my = __popcll(m & ((1ull << lane) - 1ull));
        if (l == v) {
            int pos = base + off + my;
            perm[half * 4096 + pos] = i0 + lane;
            slen[half * 4096 + pos] = v;
            ipos[half * 4096 + i0 + lane] = half * 4096 + pos;
        }
        off += __popcll(m);
    }
}

// ---- GAT h-projection
__global__ __launch_bounds__(256) void k_gat_h(
        const unsigned short* Wat, const float* node_emb,
        const int* in_nodes, const int* out_nodes, unsigned short* ht) {
    __shared__ __align__(16) unsigned short At[64][32 + PADW];
    __shared__ __align__(16) unsigned short Bt[64][32 + PADW];
    int nb = blockIdx.x, mb = blockIdx.y, g = blockIdx.z;
    const int* nodes = g ? out_nodes : in_nodes;
    int tid = threadIdx.x, wave = tid >> 6, lane = tid & 63;
    int wn = wave >> 1, wm = wave & 1;
    int r = tid >> 2, seg = (tid & 3) * 8;
    int node = nodes[mb * 64 + r];
    const float* bsrc = node_emb + (size_t)node * 512 + seg;
    const unsigned short* asrc = Wat + (size_t)(nb * 64 + r) * 512 + seg;
    f32x4 z4 = {0.f, 0.f, 0.f, 0.f};
    f32x4 acc[2][2];
#pragma unroll
    for (int a = 0; a < 2; a++)
#pragma unroll
        for (int b = 0; b < 2; b++) acc[a][b] = z4;
    for (int k0 = 0; k0 < 512; k0 += 32) {
        __syncthreads();
        *(uint4*)&At[r][seg] = *(const uint4*)(asrc + k0);
        float4 lo = *(const float4*)(bsrc + k0);
        float4 hi = *(const float4*)(bsrc + k0 + 4);
        alignas(16) unsigned short t8[8] = {
            f2b(lo.x), f2b(lo.y), f2b(lo.z), f2b(lo.w),
            f2b(hi.x), f2b(hi.y), f2b(hi.z), f2b(hi.w)};
        *(uint4*)&Bt[r][seg] = *(uint4*)t8;
        __syncthreads();
#pragma unroll
        for (int nf = 0; nf < 2; nf++) {
            bf16x8 a = *(bf16x8*)&At[wn * 32 + nf * 16 + (lane & 15)][(lane >> 4) * 8];
#pragma unroll
            for (int mf = 0; mf < 2; mf++) {
                bf16x8 b = *(bf16x8*)&Bt[wm * 32 + mf * 16 + (lane & 15)][(lane >> 4) * 8];
                acc[nf][mf] = __builtin_amdgcn_mfma_f32_16x16x32_bf16(a, b, acc[nf][mf], 0, 0, 0);
            }
        }
    }
    unsigned short* htg = ht + (size_t)g * 4 * 128 * 4096;
#pragma unroll
    for (int nf = 0; nf < 2; nf++)
#pragma unroll
        for (int mf = 0; mf < 2; mf++) {
            int i = mb * 64 + wm * 32 + mf * 16 + (lane & 15);
            int n0 = nb * 64 + wn * 32 + nf * 16 + (lane >> 4) * 4;
#pragma unroll
            for (int q = 0; q < 4; q++)
                htg[(size_t)(n0 + q) * 4096 + i] = f2b(acc[nf][mf][q]);
        }
}

// ---- f1/f2
__global__ void k_f12(const unsigned short* ht, const float* a1,
                      const float* a2, float* f1, float* f2) {
    int idx = blockIdx.x * 256 + threadIdx.x;
    int i = idx & 4095;
    int h = (idx >> 12) & 3;
    const unsigned short* p = ht + (size_t)(idx >> 12) * 128 * 4096 + i;
    float s1 = 0.f, s2 = 0.f;
    for (int d = 0; d < 128; d++) {
        float v = b2f(p[(size_t)d * 4096]);
        s1 += v * a1[h * 128 + d];
        s2 += v * a2[h * 128 + d];
    }
    f1[idx] = s1; f2[idx] = s2;
}

// ---- GAT PV, split-j x2, A-tile register prefetch
__global__ __launch_bounds__(256) void k_gat_pv_split2(
        const unsigned short* ht, const unsigned long long* bits,
        const float* f1, const float* f2, float* partO, float* partS) {
    __shared__ __align__(16) unsigned short At[128][64 + PADW];
    __shared__ __align__(16) unsigned short Pt[64][64 + PADW];
    int mb = blockIdx.x, hh = blockIdx.y, g = blockIdx.z;
    int h = hh >> 1, js = hh & 1;
    int tid = threadIdx.x, wave = tid >> 6, lane = tid & 63;
    int wn = wave >> 1, wm = wave & 1;
    const unsigned short* htp = ht + (size_t)(g * 4 + h) * 128 * 4096;
    const float* f2p = f2 + (size_t)(g * 4 + h) * 4096;
    const unsigned long long* bitp = bits + (size_t)g * 4096 * 64 + (size_t)(mb * 64) * 64;
    int iloc = tid >> 2, jc = tid & 3;
    float myf1 = f1[(size_t)(g * 4 + h) * 4096 + mb * 64 + iloc];
    float s_acc = 0.f;
    f32x4 z4 = {0.f, 0.f, 0.f, 0.f};
    f32x4 acc[4][2];
#pragma unroll
    for (int a = 0; a < 4; a++)
#pragma unroll
        for (int b = 0; b < 2; b++) acc[a][b] = z4;
    int pd = tid >> 3, psg = (tid & 7) * 8;
    uint4 apre[4];
#pragma unroll
    for (int q = 0; q < 4; q++)
        apre[q] = *(const uint4*)(htp + (size_t)(pd + q * 32) * 4096 + (js << 11) + psg);
    for (int jt = 0; jt < 32; jt++) {
        int j0 = (js << 11) + (jt << 6);
        __syncthreads();
#pragma unroll
        for (int q = 0; q < 4; q++)
            *(uint4*)&At[pd + q * 32][psg] = apre[q];
        unsigned long long w = bitp[(size_t)iloc * 64 + (j0 >> 6)] >> (jc * 16);
        float fv[16];
#pragma unroll
        for (int q = 0; q < 4; q++) {
            float4 vv = *(const float4*)(f2p + j0 + jc * 16 + q * 4);
            fv[q * 4 + 0] = vv.x; fv[q * 4 + 1] = vv.y;
            fv[q * 4 + 2] = vv.z; fv[q * 4 + 3] = vv.w;
        }
        alignas(16) unsigned short pv[16];
        float rs = 0.f;
#pragma unroll
        for (int e = 0; e < 16; e++) {
            float ee = myf1 + fv[e];
            ee = ee > 0.f ? ee : 0.2f * ee;
            float pval = ((w >> e) & 1ull) ? __expf(ee) : 0.f;
            rs += pval;
            pv[e] = f2b(pval);
        }
        rs += __shfl_xor(rs, 1);
        rs += __shfl_xor(rs, 2);
        s_acc += rs;
        *(uint4*)&Pt[iloc][jc * 16] = *(uint4*)&pv[0];
        *(uint4*)&Pt[iloc][jc * 16 + 8] = *(uint4*)&pv[8];
        __syncthreads();
        if (jt + 1 < 32) {
            int j1 = (js << 11) + ((jt + 1) << 6);
#pragma unroll
            for (int q = 0; q < 4; q++)
                apre[q] = *(const uint4*)(htp + (size_t)(pd + q * 32) * 4096 + j1 + psg);
        }
#pragma unroll
        for (int ks = 0; ks < 2; ks++) {
            bf16x8 bfr[2];
#pragma unroll
            for (int mf = 0; mf < 2; mf++)
                bfr[mf] = *(bf16x8*)&Pt[wm * 32 + mf * 16 + (lane & 15)][ks * 32 + (lane >> 4) * 8];
#pragma unroll
            for (int nf = 0; nf < 4; nf++) {
                bf16x8 a = *(bf16x8*)&At[wn * 64 + nf * 16 + (lane & 15)][ks * 32 + (lane >> 4) * 8];
#pragma unroll
                for (int mf = 0; mf < 2; mf++)
                    acc[nf][mf] = __builtin_amdgcn_mfma_f32_16x16x32_bf16(a, bfr[mf], acc[nf][mf], 0, 0, 0);
            }
        }
    }
    int slab = ((g * 4 + h) * 2 + js);
    if ((tid & 3) == 0)
        partS[(size_t)slab * 4096 + mb * 64 + iloc] = s_acc;
#pragma unroll
    for (int nf = 0; nf < 4; nf++)
#pragma unroll
        for (int mf = 0; mf < 2; mf++) {
            int il = wm * 32 + mf * 16 + (lane & 15);
            int i = mb * 64 + il;
            int d0 = wn * 64 + nf * 16 + (lane >> 4) * 4;
            float4 v;
            v.x = acc[nf][mf][0];
            v.y = acc[nf][mf][1];
            v.z = acc[nf][mf][2];
            v.w = acc[nf][mf][3];
            *(float4*)&partO[((size_t)slab * 4096 + i) * 128 + d0] = v;
        }
}

// ---- combine pv splits (x2)
__global__ void k_pv_combine(const float* partO, const float* partS, float* emb) {
    int idx = blockIdx.x * 256 + threadIdx.x;
    int d = idx & 127;
    int i = (idx >> 7) & 4095;
    int h = (idx >> 19) & 3;
    int g = idx >> 21;
    float s = 0.f, v = 0.f;
#pragma unroll
    for (int js = 0; js < 2; js++) {
        int slab = (g * 4 + h) * 2 + js;
        s += partS[(size_t)slab * 4096 + i];
        v += partO[((size_t)slab * 4096 + i) * 128 + d];
    }
    emb[((size_t)g * 4096 + i) * 512 + h * 128 + d] = s > 0.f ? v / s : 0.f;
}

// ---- GAT PV full (tier C fallback)
__global__ __launch_bounds__(256) void k_gat_pv_full(
        const unsigned short* ht, const unsigned long long* bits,
        const float* f1, const float* f2, float* emb) {
    __shared__ __align__(16) unsigned short At[128][64 + PADW];
    __shared__ __align__(16) unsigned short Pt[64][64 + PADW];
    __shared__ float s_lds[64];
    int mb = blockIdx.x, h = blockIdx.y, g = blockIdx.z;
    int tid = threadIdx.x, wave = tid >> 6, lane = tid & 63;
    int wn = wave >> 1, wm = wave & 1;
    const unsigned short* htp = ht + (size_t)(g * 4 + h) * 128 * 4096;
    const float* f2p = f2 + (size_t)(g * 4 + h) * 4096;
    const unsigned long long* bitp = bits + (size_t)g * 4096 * 64 + (size_t)(mb * 64) * 64;
    int iloc = tid >> 2, jc = tid & 3;
    float myf1 = f1[(size_t)(g * 4 + h) * 4096 + mb * 64 + iloc];
    float s_acc = 0.f;
    f32x4 z4 = {0.f, 0.f, 0.f, 0.f};
    f32x4 acc[4][2];
#pragma unroll
    for (int a = 0; a < 4; a++)
#pragma unroll
        for (int b = 0; b < 2; b++) acc[a][b] = z4;
    for (int j0 = 0; j0 < 4096; j0 += 64) {
        __syncthreads();
#pragma unroll
        for (int q = 0; q < 4; q++) {
            int c = tid + q * 256;
            int d = c >> 3, sg = (c & 7) * 8;
            *(uint4*)&At[d][sg] = *(const uint4*)(htp + (size_t)d * 4096 + j0 + sg);
        }
        unsigned long long w = bitp[(size_t)iloc * 64 + (j0 >> 6)] >> (jc * 16);
        float fv[16];
#pragma unroll
        for (int q = 0; q < 4; q++) {
            float4 vv = *(const float4*)(f2p + j0 + jc * 16 + q * 4);
            fv[q * 4 + 0] = vv.x; fv[q * 4 + 1] = vv.y;
            fv[q * 4 + 2] = vv.z; fv[q * 4 + 3] = vv.w;
        }
        alignas(16) unsigned short pv[16];
        float rs = 0.f;
#pragma unroll
        for (int e = 0; e < 16; e++) {
            float ee = myf1 + fv[e];
            ee = ee > 0.f ? ee : 0.2f * ee;
            float pval = ((w >> e) & 1ull) ? __expf(ee) : 0.f;
            rs += pval;
            pv[e] = f2b(pval);
        }
        rs += __shfl_xor(rs, 1);
        rs += __shfl_xor(rs, 2);
        s_acc += rs;
        *(uint4*)&Pt[iloc][jc * 16] = *(uint4*)&pv[0];
        *(uint4*)&Pt[iloc][jc * 16 + 8] = *(uint4*)&pv[8];
        __syncthreads();
#pragma unroll
        for (int ks = 0; ks < 2; ks++) {
            bf16x8 bfr[2];
#pragma unroll
            for (int mf = 0; mf < 2; mf++)
                bfr[mf] = *(bf16x8*)&Pt[wm * 32 + mf * 16 + (lane & 15)][ks * 32 + (lane >> 4) * 8];
#pragma unroll
            for (int nf = 0; nf < 4; nf++) {
                bf16x8 a = *(bf16x8*)&At[wn * 64 + nf * 16 + (lane & 15)][ks * 32 + (lane >> 4) * 8];
#pragma unroll
                for (int mf = 0; mf < 2; mf++)
                    acc[nf][mf] = __builtin_amdgcn_mfma_f32_16x16x32_bf16(a, bfr[mf], acc[nf][mf], 0, 0, 0);
            }
        }
    }
    if ((tid & 3) == 0) s_lds[iloc] = s_acc;
    __syncthreads();
    float* embp = emb + (size_t)g * 4096 * 512;
#pragma unroll
    for (int nf = 0; nf < 4; nf++)
#pragma unroll
        for (int mf = 0; mf < 2; mf++) {
            int il = wm * 32 + mf * 16 + (lane & 15);
            float sv = s_lds[il];
            float inv = sv > 0.f ? 1.f / sv : 0.f;
            int i = mb * 64 + il;
            int d0 = wn * 64 + nf * 16 + (lane >> 4) * 4;
            float4 v;
            v.x = acc[nf][mf][0] * inv;
            v.y = acc[nf][mf][1] * inv;
            v.z = acc[nf][mf][2] * inv;
            v.w = acc[nf][mf][3] * inv;
            *(float4*)&embp[(size_t)i * 512 + h * 128 + d0] = v;
        }
}

// ---- head/tail gather + elu
__global__ void k_headtail(const float* emb, const int* imh, const int* omh,
                           const int* imt, const int* omt, unsigned short* hcat) {
    int idx = blockIdx.x * 256 + threadIdx.x;
    if (idx >= 2 * 1024 * 512) return;
    int which = idx >> 19;
    int o = idx & 524287;
    int b = o >> 9, c = o & 511;
    int i0 = which ? imt[b] : imh[b];
    int i1 = which ? omt[b] : omh[b];
    float v = emb[(size_t)i0 * 512 + c] + emb[(size_t)(4096 + i1) * 512 + c];
    v = v > 0.f ? v : (__expf(v) - 1.f);
    hcat[(size_t)which * 1024 * 1024 + (size_t)b * 1024 + c] = f2b(v);
}

// ---- gi vocab table v2 + register-prefetch pipeline
__global__ __launch_bounds__(256) void k_gi2(
        const unsigned short* wz, const float* word_emb,
        const unsigned short* wemb16, int use16, unsigned short* giTab) {
    __shared__ __align__(16) unsigned short At[128][32 + PADW];
    __shared__ __align__(16) unsigned short Bt[128][32 + PADW];
    int b = blockIdx.x;
    int xcd = b & 7, s = b >> 3;
    int nb = s % 12;
    int wbg = xcd * 63 + s / 12;
    if (wbg >= 500) return;
    int wb = wbg >> 1, g = wbg & 1;
    const unsigned short* Wi = wz + (size_t)(g ? 2 : 0) * 786432;
    int tid = threadIdx.x, wave = tid >> 6, lane = tid & 63;
    int wn = wave >> 1, wm = wave & 1;
    int r = tid >> 1, h2 = tid & 1;
    const unsigned short* asrc = Wi + (size_t)(nb * 128 + r) * 512 + h2 * 16;
    const unsigned short* bsrc16 = wemb16 + (size_t)(wb * 128 + r) * 512 + h2 * 16;
    const float* bsrc32 = word_emb + (size_t)(wb * 128 + r) * 512 + h2 * 16;
    f32x4 z4 = {0.f, 0.f, 0.f, 0.f};
    f32x4 acc[4][4];
#pragma unroll
    for (int a = 0; a < 4; a++)
#pragma unroll
        for (int c = 0; c < 4; c++) acc[a][c] = z4;
    uint4 apre0, apre1, bpre0, bpre1;
    float4 fp0, fp1, fp2v, fp3;
    apre0 = ((const uint4*)asrc)[0];
    apre1 = *(const uint4*)(asrc + 8);
    if (use16) {
        bpre0 = ((const uint4*)bsrc16)[0];
        bpre1 = *(const uint4*)(bsrc16 + 8);
    } else {
        fp0 = ((const float4*)bsrc32)[0]; fp1 = ((const float4*)bsrc32)[1];
        fp2v = ((const float4*)bsrc32)[2]; fp3 = ((const float4*)bsrc32)[3];
    }
    for (int k0 = 0; k0 < 512; k0 += 32) {
        __syncthreads();
        *(uint4*)&At[r][h2 * 16]     = apre0;
        *(uint4*)&At[r][h2 * 16 + 8] = apre1;
        if (use16) {
            *(uint4*)&Bt[r][h2 * 16]     = bpre0;
            *(uint4*)&Bt[r][h2 * 16 + 8] = bpre1;
        } else {
            alignas(16) unsigned short t16[16] = {
                f2b(fp0.x), f2b(fp0.y), f2b(fp0.z), f2b(fp0.w),
                f2b(fp1.x), f2b(fp1.y), f2b(fp1.z), f2b(fp1.w),
                f2b(fp2v.x), f2b(fp2v.y), f2b(fp2v.z), f2b(fp2v.w),
                f2b(fp3.x), f2b(fp3.y), f2b(fp3.z), f2b(fp3.w)};
            *(uint4*)&Bt[r][h2 * 16]     = ((uint4*)t16)[0];
            *(uint4*)&Bt[r][h2 * 16 + 8] = ((uint4*)t16)[1];
        }
        __syncthreads();
        if (k0 + 32 < 512) {
            int k1 = k0 + 32;
            apre0 = *(const uint4*)(asrc + k1);
            apre1 = *(const uint4*)(asrc + k1 + 8);
            if (use16) {
                bpre0 = *(const uint4*)(bsrc16 + k1);
                bpre1 = *(const uint4*)(bsrc16 + k1 + 8);
            } else {
                fp0 = ((const float4*)(bsrc32 + k1))[0];
                fp1 = ((const float4*)(bsrc32 + k1))[1];
                fp2v = ((const float4*)(bsrc32 + k1))[2];
                fp3 = ((const float4*)(bsrc32 + k1))[3];
            }
        }
        bf16x8 av[4], bv[4];
#pragma unroll
        for (int nf = 0; nf < 4; nf++)
            av[nf] = *(bf16x8*)&At[wn * 64 + nf * 16 + (lane & 15)][(lane >> 4) * 8];
#pragma unroll
        for (int mf = 0; mf < 4; mf++)
            bv[mf] = *(bf16x8*)&Bt[wm * 64 + mf * 16 + (lane & 15)][(lane >> 4) * 8];
#pragma unroll
        for (int nf = 0; nf < 4; nf++)
#pragma unroll
            for (int mf = 0; mf < 4; mf++)
                acc[nf][mf] = __builtin_amdgcn_mfma_f32_16x16x32_bf16(av[nf], bv[mf], acc[nf][mf], 0, 0, 0);
    }
#pragma unroll
    for (int nf = 0; nf < 4; nf++)
#pragma unroll
        for (int mf = 0; mf < 4; mf++) {
            int w = wb * 128 + wm * 64 + mf * 16 + (lane & 15);
            int n0 = nb * 128 + wn * 64 + nf * 16 + (lane >> 4) * 4;
            alignas(8) unsigned short o4[4];
#pragma unroll
            for (int q = 0; q < 4; q++) o4[q] = f2b(acc[nf][mf][q]);
            *(unsigned long long*)&giTab[((size_t)g * 32000 + w) * 1536 + n0] =
                *(unsigned long long*)o4;
        }
}

// ---- GRU step v6: BM=32, barrier-free k-loop, early NT gathers, grid 2048
__global__ __launch_bounds__(256) void k_gru_step6(
        const unsigned short* wswz, const unsigned short* giTab,
        const float* bi_in, const float* bh_in,
        const float* bi_out, const float* bh_out,
        const int* in_ctx, const int* out_ctx,
        const int* perm, const int* slen,
        const unsigned short* hb_prev, unsigned short* hb_next, float* hf,
        int t) {
    int b = blockIdx.x;                    // 2048 blocks
    int xcd = b & 7, s = b >> 3;
    int nb = s & 7;
    int mb = (s >> 3) * 8 + xcd;           // 0..255; 8 nb of an mb on one XCD
    int p0 = mb * 32;
    if (t >= slen[p0]) return;             // finished: stale hb never read
    __shared__ __align__(16) unsigned short Ht[32][512 + PADW];
    __shared__ int widx_s[32];
    __shared__ int slen_s[32];
    int tid = threadIdx.x, wave = tid >> 6, lane = tid & 63;
    int wn2 = wave >> 1, nf2 = wave & 1;   // wave -> 16-col group
    int gsel = mb >= 128;
    const int* ctx = gsel ? out_ctx : in_ctx;
    if (tid < 32) {
        int p = p0 + tid;
        int orig = perm[p];
        widx_s[tid] = ctx[orig * 64 + t];
        slen_s[tid] = slen[p];
    }
    const unsigned short* hbase = hb_prev + (size_t)p0 * 512;
#pragma unroll
    for (int j = 0; j < 8; j++) {
        int flat = tid + j * 256;          // 2048 uint4 = 32 rows x 64
        int row = flat >> 6, c16 = flat & 63;
        *(uint4*)&Ht[row][c16 * 8] = *(const uint4*)(hbase + (size_t)row * 512 + c16 * 8);
    }
    __syncthreads();
    // ---- issue gathers + hf loads EARLY
    const unsigned short* giG = giTab + (size_t)(gsel ? 32000 : 0) * 1536;
    int colbase = nb * 64 + wn2 * 32 + nf2 * 16 + (lane >> 4) * 4;
    unsigned long long gv0[2], gv1[2], gv2[2];
    float4 hold[2];
    bool validf[2];
#pragma unroll
    for (int mf = 0; mf < 2; mf++) {
        int rloc = mf * 16 + (lane & 15);
        validf[mf] = t < slen_s[rloc];
        int w = widx_s[rloc];
        const unsigned short* grow = giG + (size_t)w * 1536;
        hold[mf] = *(const float4*)&hf[(size_t)(p0 + rloc) * 512 + colbase];
        if (validf[mf]) {
            gv0[mf] = __builtin_nontemporal_load((const unsigned long long*)(grow + colbase));
            gv1[mf] = __builtin_nontemporal_load((const unsigned long long*)(grow + 512 + colbase));
            gv2[mf] = __builtin_nontemporal_load((const unsigned long long*)(grow + 1024 + colbase));
        } else {
            gv0[mf] = 0ull; gv1[mf] = 0ull; gv2[mf] = 0ull;
        }
    }
    const unsigned short* wf = wswz + (size_t)gsel * 786432 + nb * 32768
                               + wn2 * 16384 + nf2 * 8192 + (size_t)lane * 8;
    f32x4 z4 = {0.f, 0.f, 0.f, 0.f};
    f32x4 acc[3][2];
#pragma unroll
    for (int a = 0; a < 3; a++)
#pragma unroll
        for (int c = 0; c < 2; c++) acc[a][c] = z4;
#pragma unroll
    for (int kt = 0; kt < 16; kt++) {
        bf16x8 hbv[2];
#pragma unroll
        for (int mf = 0; mf < 2; mf++)
            hbv[mf] = *(bf16x8*)&Ht[mf * 16 + (lane & 15)][kt * 32 + (lane >> 4) * 8];
#pragma unroll
        for (int q = 0; q < 3; q++) {
            bf16x8 a = *(const bf16x8*)(wf + q * 262144 + kt * 512);
#pragma unroll
            for (int mf = 0; mf < 2; mf++)
                acc[q][mf] = __builtin_amdgcn_mfma_f32_16x16x32_bf16(a, hbv[mf], acc[q][mf], 0, 0, 0);
        }
    }
    const float* bi = gsel ? bi_out : bi_in;
    const float* bh = gsel ? bh_out : bh_in;
#pragma unroll
    for (int mf = 0; mf < 2; mf++) {
        int rloc = mf * 16 + (lane & 15);
        int m = p0 + rloc;
        bool valid = validf[mf];
        float ho[4] = {hold[mf].x, hold[mf].y, hold[mf].z, hold[mf].w};
        float hn[4];
        alignas(8) unsigned short hb16[4];
#pragma unroll
        for (int q = 0; q < 4; q++) {
            int n = colbase + q;
            float gir = b2f((unsigned short)(gv0[mf] >> (16 * q)));
            float giz = b2f((unsigned short)(gv1[mf] >> (16 * q)));
            float gin = b2f((unsigned short)(gv2[mf] >> (16 * q)));
            float gr = gir + bi[n] + acc[0][mf][q] + bh[n];
            float gz = giz + bi[512 + n] + acc[1][mf][q] + bh[512 + n];
            float gn = gin + bi[1024 + n];
            float ghn = acc[2][mf][q] + bh[1024 + n];
            float rr = 1.f / (1.f + __expf(-gr));
            float zz = 1.f / (1.f + __expf(-gz));
            float narg = gn + rr * ghn;
            float e2 = __expf(2.f * narg);
            float nn = 1.f - 2.f / (e2 + 1.f);
            float hv = valid ? ((1.f - zz) * nn + zz * ho[q]) : ho[q];
            hn[q] = hv;
            hb16[q] = f2b(hv);
        }
        if (valid)
            *(float4*)&hf[(size_t)m * 512 + colbase] = make_float4(hn[0], hn[1], hn[2], hn[3]);
        *(unsigned long long*)&hb_next[(size_t)m * 512 + colbase] = *(unsigned long long*)hb16;
    }
}

// ---- GRU step fused (tier C fallback)
__global__ __launch_bounds__(256) void k_gru_step_fused(
        const unsigned short* wz,
        const float* bi_in, const float* bh_in,
        const float* bi_out, const float* bh_out,
        const int* in_ctx, const int* out_ctx,
        const int* in_len, const int* out_len,
        const float* word_emb,
        const unsigned short* hb_prev, unsigned short* hb_next, float* hf,
        int t) {
    __shared__ __align__(16) unsigned short Wt[6][64][32 + PADW];
    __shared__ __align__(16) unsigned short Xt[64][32 + PADW];
    __shared__ __align__(16) unsigned short Ht[64][32 + PADW];
    int nb = blockIdx.x, mb = blockIdx.y;
    int tid = threadIdx.x, wave = tid >> 6, lane = tid & 63;
    int wn = wave >> 1, wm = wave & 1;
    int gsel = mb >= 64;
    const unsigned short* Wi = wz + (size_t)(gsel ? 2 : 0) * 786432;
    const unsigned short* Wh = wz + (size_t)(gsel ? 3 : 1) * 786432;
    const int* ctx = gsel ? out_ctx : in_ctx;
    int r = tid >> 2, seg = (tid & 3) * 8;
    int mrow = mb * 64 + r;
    int lrow = mrow - (gsel ? 4096 : 0);
    int widx = ctx[lrow * 64 + t];
    const float* xsrc = word_emb + (size_t)widx * 512 + seg;
    const unsigned short* hsrc = hb_prev + (size_t)mrow * 512 + seg;
    f32x4 z4 = {0.f, 0.f, 0.f, 0.f};
    f32x4 acc[6][2][2];
#pragma unroll
    for (int a = 0; a < 6; a++)
#pragma unroll
        for (int b = 0; b < 2; b++)
#pragma unroll
            for (int c = 0; c < 2; c++) acc[a][b][c] = z4;
    for (int k0 = 0; k0 < 512; k0 += 32) {
        __syncthreads();
#pragma unroll
        for (int q = 0; q < 6; q++) {
            const unsigned short* base = (q < 3) ? Wi : Wh;
            int gg = (q < 3) ? q : q - 3;
            *(uint4*)&Wt[q][r][seg] =
                *(const uint4*)(base + (size_t)(gg * 512 + nb * 64 + r) * 512 + k0 + seg);
        }
        float4 xlo = *(const float4*)(xsrc + k0);
        float4 xhi = *(const float4*)(xsrc + k0 + 4);
        alignas(16) unsigned short x8[8] = {
            f2b(xlo.x), f2b(xlo.y), f2b(xlo.z), f2b(xlo.w),
            f2b(xhi.x), f2b(xhi.y), f2b(xhi.z), f2b(xhi.w)};
        *(uint4*)&Xt[r][seg] = *(uint4*)x8;
        *(uint4*)&Ht[r][seg] = *(const uint4*)(hsrc + k0);
        __syncthreads();
        bf16x8 xb[2], hbv[2];
#pragma unroll
        for (int mf = 0; mf < 2; mf++) {
            xb[mf] = *(bf16x8*)&Xt[wm * 32 + mf * 16 + (lane & 15)][(lane >> 4) * 8];
            hbv[mf] = *(bf16x8*)&Ht[wm * 32 + mf * 16 + (lane & 15)][(lane >> 4) * 8];
        }
#pragma unroll
        for (int q = 0; q < 3; q++) {
#pragma unroll
            for (int nf = 0; nf < 2; nf++) {
                bf16x8 ai = *(bf16x8*)&Wt[q][wn * 32 + nf * 16 + (lane & 15)][(lane >> 4) * 8];
                bf16x8 ah = *(bf16x8*)&Wt[q + 3][wn * 32 + nf * 16 + (lane & 15)][(lane >> 4) * 8];
#pragma unroll
                for (int mf = 0; mf < 2; mf++) {
                    acc[q][nf][mf] = __builtin_amdgcn_mfma_f32_16x16x32_bf16(ai, xb[mf], acc[q][nf][mf], 0, 0, 0);
                    acc[q + 3][nf][mf] = __builtin_amdgcn_mfma_f32_16x16x32_bf16(ah, hbv[mf], acc[q + 3][nf][mf], 0, 0, 0);
                }
            }
        }
    }
    const float* bi = gsel ? bi_out : bi_in;
    const float* bh = gsel ? bh_out : bh_in;
    const int* len = gsel ? out_len : in_len;
#pragma unroll
    for (int nf = 0; nf < 2; nf++)
#pragma unroll
        for (int mf = 0; mf < 2; mf++) {
            int m = mb * 64 + wm * 32 + mf * 16 + (lane & 15);
            int lm = m - (gsel ? 4096 : 0);
            int n0 = nb * 64 + wn * 32 + nf * 16 + (lane >> 4) * 4;
            bool valid = t < len[lm];
            float4 hold4 = *(const float4*)&hf[(size_t)m * 512 + n0];
            float ho[4] = {hold4.x, hold4.y, hold4.z, hold4.w};
            float hn[4];
            alignas(8) unsigned short hb16[4];
#pragma unroll
            for (int q = 0; q < 4; q++) {
                int n = n0 + q;
                float gr = acc[0][nf][mf][q] + bi[n] + acc[3][nf][mf][q] + bh[n];
                float gz = acc[1][nf][mf][q] + bi[512 + n] + acc[4][nf][mf][q] + bh[512 + n];
                float gn = acc[2][nf][mf][q] + bi[1024 + n];
                float ghn = acc[5][nf][mf][q] + bh[1024 + n];
                float rr = 1.f / (1.f + __expf(-gr));
                float zz = 1.f / (1.f + __expf(-gz));
                float narg = gn + rr * ghn;
                float e2 = __expf(2.f * narg);
                float nn = 1.f - 2.f / (e2 + 1.f);
                float hv = valid ? ((1.f - zz) * nn + zz * ho[q]) : ho[q];
                hn[q] = hv;
                hb16[q] = f2b(hv);
            }
            *(float4*)&hf[(size_t)m * 512 + n0] = make_float4(hn[0], hn[1], hn[2], hn[3]);
            *(unsigned long long*)&hb_next[(size_t)m * 512 + n0] = *(unsigned long long*)hb16;
        }
}

// ---- ctx average (permuted via ipos)
__global__ void k_avgcat2(const float* hf, const int* ipos, unsigned short* hcat) {
    int idx = blockIdx.x * 256 + threadIdx.x;
    if (idx >= 1024 * 512) return;
    int b = idx >> 9, c = idx & 511;
    float si = 0.f, so = 0.f;
#pragma unroll
    for (int cc = 0; cc < 4; cc++) {
        si += hf[(size_t)ipos[b * 4 + cc] * 512 + c];
        so += hf[(size_t)ipos[4096 + b * 4 + cc] * 512 + c];
    }
    hcat[(size_t)b * 1024 + 512 + c] = f2b(so * 0.25f);
    hcat[(size_t)1024 * 1024 + (size_t)b * 1024 + 512 + c] = f2b(si * 0.25f);
}

// ---- ctx average plain (tier C)
__global__ void k_avgcat(const float* hf, unsigned short* hcat) {
    int idx = blockIdx.x * 256 + threadIdx.x;
    if (idx >= 1024 * 512) return;
    int b = idx >> 9, c = idx & 511;
    float si = 0.f, so = 0.f;
#pragma unroll
    for (int cc = 0; cc < 4; cc++) {
        si += hf[(size_t)(b * 4 + cc) * 512 + c];
        so += hf[(size_t)(4096 + b * 4 + cc) * 512 + c];
    }
    hcat[(size_t)b * 1024 + 512 + c] = f2b(so * 0.25f);
    hcat[(size_t)1024 * 1024 + (size_t)b * 1024 + 512 + c] = f2b(si * 0.25f);
}

// ---- final heads
__global__ __launch_bounds__(256) void k_final(
        const unsigned short* lgT, const unsigned short* hcat,
        const float* link_b, const float* gen_b, float* out) {
    __shared__ __align__(16) unsigned short At[64][32 + PADW];
    __shared__ __align__(16) unsigned short Bt[64][32 + PADW];
    int nb = blockIdx.x, mb = blockIdx.y, z = blockIdx.z;
    int wsel = z >> 1, asel = z & 1;
    const unsigned short* W = lgT + (size_t)wsel * 512 * 1024;
    const unsigned short* A = hcat + (size_t)asel * 1024 * 1024;
    const float* bias = wsel ? gen_b : link_b;
    int tid = threadIdx.x, wave = tid >> 6, lane = tid & 63;
    int wn = wave >> 1, wm = wave & 1;
    int r = tid >> 2, seg = (tid & 3) * 8;
    f32x4 z4 = {0.f, 0.f, 0.f, 0.f};
    f32x4 acc[2][2];
#pragma unroll
    for (int a = 0; a < 2; a++)
#pragma unroll
        for (int b = 0; b < 2; b++) acc[a][b] = z4;
    for (int k0 = 0; k0 < 1024; k0 += 32) {
        __syncthreads();
        *(uint4*)&At[r][seg] = *(const uint4*)(W + (size_t)(nb * 64 + r) * 1024 + k0 + seg);
        *(uint4*)&Bt[r][seg] = *(const uint4*)(A + (size_t)(mb * 64 + r) * 1024 + k0 + seg);
        __syncthreads();
#pragma unroll
        for (int nf = 0; nf < 2; nf++) {
            bf16x8 a = *(bf16x8*)&At[wn * 32 + nf * 16 + (lane & 15)][(lane >> 4) * 8];
#pragma unroll
            for (int mf = 0; mf < 2; mf++) {
                bf16x8 b = *(bf16x8*)&Bt[wm * 32 + mf * 16 + (lane & 15)][(lane >> 4) * 8];
                acc[nf][mf] = __builtin_amdgcn_mfma_f32_16x16x32_bf16(a, b, acc[nf][mf], 0, 0, 0);
            }
        }
    }
#pragma unroll
    for (int nf = 0; nf < 2; nf++)
#pragma unroll
        for (int mf = 0; mf < 2; mf++) {
            int m = mb * 64 + wm * 32 + mf * 16 + (lane & 15);
            int n0 = nb * 64 + wn * 32 + nf * 16 + (lane >> 4) * 4;
            float4 v;
            v.x = acc[nf][mf][0] + bias[n0 + 0];
            v.y = acc[nf][mf][1] + bias[n0 + 1];
            v.z = acc[nf][mf][2] + bias[n0 + 2];
            v.w = acc[nf][mf][3] + bias[n0 + 3];
            *(float4*)&out[(size_t)z * 524288 + (size_t)m * 512 + n0] = v;
        }
}

extern "C" void kernel_launch(void* const* d_in, const int* in_sizes, int n_in,
                              void* d_out, int out_size, void* d_ws, size_t ws_size,
                              hipStream_t stream) {
    const int* in_nodes   = (const int*)d_in[0];
    const int* out_nodes  = (const int*)d_in[1];
    const int* inner_adj  = (const int*)d_in[2];
    const int* outer_adj  = (const int*)d_in[3];
    const int* in_map_hs  = (const int*)d_in[4];
    const int* in_map_ts  = (const int*)d_in[5];
    const int* out_map_hs = (const int*)d_in[6];
    const int* out_map_ts = (const int*)d_in[7];
    const int* in_ctx     = (const int*)d_in[8];
    const int* in_len     = (const int*)d_in[9];
    const int* out_ctx    = (const int*)d_in[10];
    const int* out_len    = (const int*)d_in[11];
    const float* node_emb = (const float*)d_in[14];
    const float* word_emb = (const float*)d_in[15];
    const float* W_att    = (const float*)d_in[16];
    const float* a1       = (const float*)d_in[17];
    const float* a2       = (const float*)d_in[18];
    const float* gi_Wi    = (const float*)d_in[19];
    const float* gi_Wh    = (const float*)d_in[20];
    const float* gi_bi    = (const float*)d_in[21];
    const float* gi_bh    = (const float*)d_in[22];
    const float* go_Wi    = (const float*)d_in[23];
    const float* go_Wh    = (const float*)d_in[24];
    const float* go_bi    = (const float*)d_in[25];
    const float* go_bh    = (const float*)d_in[26];
    const float* link_W   = (const float*)d_in[27];
    const float* link_b   = (const float*)d_in[28];
    const float* gen_W    = (const float*)d_in[29];
    const float* gen_b    = (const float*)d_in[30];

    char* p = (char*)d_ws;
    auto alloc = [&](size_t bytes) {
        char* r = p;
        p += (bytes + 255) & ~(size_t)255;
        return r;
    };
    unsigned short*      Wat  = (unsigned short*)alloc((size_t)512 * 512 * 2);
    unsigned short*      lgT  = (unsigned short*)alloc((size_t)2 * 512 * 1024 * 2);
    unsigned short*      wz   = (unsigned short*)alloc((size_t)4 * 786432 * 2);
    unsigned long long*  bits = (unsigned long long*)alloc((size_t)2 * 4096 * 64 * 8);
    unsigned short*      ht   = (unsigned short*)alloc((size_t)2 * 4 * 128 * 4096 * 2);
    float*               f1   = (float*)alloc((size_t)2 * 4 * 4096 * 4);
    float*               f2   = (float*)alloc((size_t)2 * 4 * 4096 * 4);
    float*               emb  = (float*)alloc((size_t)2 * 4096 * 512 * 4);
    float*               hf   = (float*)alloc((size_t)8192 * 512 * 4);
    unsigned short*      hb   = (unsigned short*)alloc((size_t)2 * 8192 * 512 * 2);
    unsigned short*      hcat = (unsigned short*)alloc((size_t)2 * 1024 * 1024 * 2);
    size_t need_base = (size_t)(p - (char*)d_ws);
    unsigned short*      wswz = (unsigned short*)alloc((size_t)2 * 786432 * 2);
    unsigned short*      giTab = (unsigned short*)alloc((size_t)2 * 32000 * 1536 * 2);
    size_t need_main = (size_t)(p - (char*)d_ws);
    unsigned short*      wemb16 = (unsigned short*)alloc((size_t)32000 * 512 * 2);
    size_t need_tierA = (size_t)(p - (char*)d_ws);
    // pv partials alias giTab (pv runs before k_gi2); 16 slabs x 4096 x 128 f32
    float* partO = (float*)giTab;
    float* partS = (float*)((char*)giTab + (size_t)16 * 4096 * 128 * 4);
    // sort arrays alias bits (bits dead after pv_split)
    int* perm = (int*)bits;
    int* slen = perm + 8192;
    int* ipos = slen + 8192;

    bool tierA = ws_size >= need_tierA;
    bool tierB = ws_size >= need_main;
    if (!tierB && ws_size < need_base) return;  // workspace too small

    k_prep_wat<<<1024, 256, 0, stream>>>(W_att, Wat);
    k_prep_lg<<<4096, 256, 0, stream>>>(link_W, gen_W, lgT);
    k_prep_gruw<<<12288, 256, 0, stream>>>(gi_Wi, gi_Wh, go_Wi, go_Wh, wz);
    k_bitpack<<<2048, 256, 0, stream>>>(inner_adj, outer_adj, bits);
    k_zero<<<16384, 256, 0, stream>>>(hf, hb);
    k_gat_h<<<dim3(8, 64, 2), 256, 0, stream>>>(Wat, node_emb, in_nodes, out_nodes, ht);
    k_f12<<<128, 256, 0, stream>>>(ht, a1, a2, f1, f2);

    if (tierB) {
        k_prep_whfrag<<<6144, 256, 0, stream>>>(gi_Wh, go_Wh, wswz);
        if (tierA) k_prep_wemb<<<8000, 256, 0, stream>>>(word_emb, wemb16);
        k_gat_pv_split2<<<dim3(64, 8, 2), 256, 0, stream>>>(ht, bits, f1, f2, partO, partS);
        k_pv_combine<<<16384, 256, 0, stream>>>(partO, partS, emb);
        k_sort<<<128, 64, 0, stream>>>(in_len, out_len, perm, slen, ipos);
        k_gi2<<<6048, 256, 0, stream>>>(wz, word_emb,
                                        tierA ? wemb16 : (const unsigned short*)nullptr,
                                        tierA ? 1 : 0, giTab);
        k_headtail<<<4096, 256, 0, stream>>>(emb, in_map_hs, out_map_hs, in_map_ts, out_map_ts, hcat);
        for (int t = 0; t < 64; t++) {
            const unsigned short* hp = hb + (size_t)(t & 1) * 8192 * 512;
            unsigned short* hn = hb + (size_t)((t & 1) ^ 1) * 8192 * 512;
            k_gru_step6<<<2048, 256, 0, stream>>>(
                wswz, giTab, gi_bi, gi_bh, go_bi, go_bh,
                in_ctx, out_ctx, perm, slen, hp, hn, hf, t);
        }
        k_avgcat2<<<2048, 256, 0, stream>>>(hf, ipos, hcat);
    } else {
        k_gat_pv_full<<<dim3(64, 4, 2), 256, 0, stream>>>(ht, bits, f1, f2, emb);
        k_headtail<<<4096, 256, 0, stream>>>(emb, in_map_hs, out_map_hs, in_map_ts, out_map_ts, hcat);
        for (int t = 0; t < 64; t++) {
            const unsigned short* hp = hb + (size_t)(t & 1) * 8192 * 512;
            unsigned short* hn = hb + (size_t)((t & 1) ^ 1) * 8192 * 512;
            k_gru_step_fused<<<dim3(8, 128), 256, 0, stream>>>(
                wz, gi_bi, gi_bh, go_bi, go_bh,
                in_ctx, out_ctx, in_len, out_len, word_emb, hp, hn, hf, t);
        }
        k_avgcat<<<2048, 256, 0, stream>>>(hf, hcat);
    }
    k_final<<<dim3(8, 16, 4), 256, 0, stream>>>(lgT, hcat, link_b, gen_b,
                                                (float*)d_out);
}

// Round 15
// 2284.602 us; speedup vs baseline: 1.0047x; 1.0047x over previous
//
#include <hip/hip_runtime.h>
#include <hip/hip_cooperative_groups.h>
#include <stdint.h>

namespace cg = cooperative_groups;

// ---------------------------------------------------------------------------
// Encoder (GAT + 2x GRU + link/gen heads), MI355X. FP32 I/O, bf16 MFMA inside.
// R15: k_gru_coop — one cooperative kernel for all 64 GRU steps, keeping
// step6's exact block decomposition (nb-split, BM=32, XCD-grouped). fp32 h
// master in registers (hf round-trip eliminated); hb ping-pong + grid.sync()
// per step; block handles 2 mb-tiles (mbase, mbase+128) for 1024-block
// co-residency (4/CU, LDS 34KB, VGPR<=128). Occupancy-checked fallback to
// the R14 step6 loop.
// ---------------------------------------------------------------------------

typedef __attribute__((ext_vector_type(8))) short bf16x8;
typedef __attribute__((ext_vector_type(4))) float f32x4;

#define PADW 8

__device__ __forceinline__ unsigned short f2b(float f) {
    union { float f; unsigned int u; } v; v.f = f;
    return (unsigned short)((v.u + 0x7fffu + ((v.u >> 16) & 1u)) >> 16);
}
__device__ __forceinline__ float b2f(unsigned short b) {
    union { unsigned int u; float f; } v; v.u = ((unsigned int)b) << 16;
    return v.f;
}

// ---- prep: Wat[n=h*128+d][k] = bf16(W_att[h][k][d])
__global__ void k_prep_wat(const float* watt, unsigned short* dst) {
    int idx = blockIdx.x * 256 + threadIdx.x;
    if (idx >= 512 * 512) return;
    int n = idx >> 9, k = idx & 511;
    int h = n >> 7, d = n & 127;
    dst[idx] = f2b(watt[(h * 512 + k) * 128 + d]);
}

// ---- prep: lgT[s][n][k] = bf16((s?genW:linkW)[k][n])
__global__ void k_prep_lg(const float* linkW, const float* genW,
                          unsigned short* dst) {
    int idx = blockIdx.x * 256 + threadIdx.x;
    if (idx >= 2 * 512 * 1024) return;
    int s = idx >> 19;
    int o = idx & 524287;
    int n = o >> 10, k = o & 1023;
    const float* W = s ? genW : linkW;
    dst[idx] = f2b(W[k * 512 + n]);
}

// ---- prep: wz = bf16 copies of [gi_Wi, gi_Wh, go_Wi, go_Wh], each 1536x512
__global__ void k_prep_gruw(const float* a, const float* b, const float* c,
                            const float* d, unsigned short* dst) {
    int idx = blockIdx.x * 256 + threadIdx.x;
    if (idx >= 4 * 786432) return;
    int s = idx / 786432, o = idx % 786432;
    const float* src = (s == 0) ? a : (s == 1) ? b : (s == 2) ? c : d;
    dst[idx] = f2b(src[o]);
}

// ---- prep: Wh in MFMA-fragment order
__global__ void k_prep_whfrag(const float* wh_in, const float* wh_out,
                              unsigned short* dst) {
    int idx = blockIdx.x * 256 + threadIdx.x;
    if (idx >= 2 * 786432) return;
    int g = idx / 786432;
    int r2 = idx % 786432;
    int q = r2 / 262144;
    int r3 = r2 % 262144;
    int nb = r3 >> 15;
    int wn = (r3 >> 14) & 1;
    int nf = (r3 >> 13) & 1;
    int kt = (r3 >> 9) & 15;
    int lane = (r3 >> 3) & 63;
    int e = r3 & 7;
    int row = q * 512 + nb * 64 + wn * 32 + nf * 16 + (lane & 15);
    int col = kt * 32 + (lane >> 4) * 8 + e;
    const float* src = g ? wh_out : wh_in;
    dst[idx] = f2b(src[row * 512 + col]);
}

// ---- prep: bf16 copy of word_emb (tier A)
__global__ void k_prep_wemb(const float* we, unsigned short* dst) {
    int idx = blockIdx.x * 256 + threadIdx.x;
    if (idx >= 2048000) return;
    const float* s = we + (size_t)idx * 8;
    float4 a = ((const float4*)s)[0], b = ((const float4*)s)[1];
    alignas(16) unsigned short t8[8] = {
        f2b(a.x), f2b(a.y), f2b(a.z), f2b(a.w),
        f2b(b.x), f2b(b.y), f2b(b.z), f2b(b.w)};
    *(uint4*)&dst[(size_t)idx * 8] = *(uint4*)t8;
}

// ---- bitpack adjacency
__global__ void k_bitpack(const int* inner, const int* outer, unsigned long long* bits) {
    int row = blockIdx.x * 4 + (threadIdx.x >> 6);
    int lane = threadIdx.x & 63;
    int g = row >> 12, i = row & 4095;
    const int* adj = (g ? outer : inner) + (size_t)i * 4096;
    unsigned long long* d = bits + (size_t)row * 64;
    for (int w = 0; w < 64; w++) {
        int v = adj[w * 64 + lane];
        unsigned long long m = __ballot(v != 0);
        if (lane == 0) d[w] = m;
    }
}

// ---- zero h state
__global__ void k_zero(float* hf, unsigned short* hb0) {
    int idx = blockIdx.x * 256 + threadIdx.x;
    if (idx < 8192 * 512) { hf[idx] = 0.f; hb0[idx] = 0; }
}

// ---- stable counting sort by len (descending), per half
__global__ void k_sort(const int* in_len, const int* out_len,
                       int* perm, int* slen, int* ipos) {
    int bid = blockIdx.x;
    int half = bid >> 6;
    int v = 64 - (bid & 63);
    const int* len = half ? out_len : in_len;
    int lane = threadIdx.x;
    int base = 0;
    for (int i0 = 0; i0 < 4096; i0 += 64) {
        unsigned long long m = __ballot(len[i0 + lane] > v);
        base += __popcll(m);
    }
    int off = 0;
    for (int i0 = 0; i0 < 4096; i0 += 64) {
        int l = len[i0 + lane];
        unsigned long long m = __ballot(l == v);
        int my = __popcll(m & ((1ull << lane) - 1ull));
        if (l == v) {
            int pos = base + off + my;
            perm[half * 4096 + pos] = i0 + lane;
            slen[half * 4096 + pos] = v;
            ipos[half * 4096 + i0 + lane] = half * 4096 + pos;
        }
        off += __popcll(m);
    }
}

// ---- GAT h-projection
__global__ __launch_bounds__(256) void k_gat_h(
        const unsigned short* Wat, const float* node_emb,
        const int* in_nodes, const int* out_nodes, unsigned short* ht) {
    __shared__ __align__(16) unsigned short At[64][32 + PADW];
    __shared__ __align__(16) unsigned short Bt[64][32 + PADW];
    int nb = blockIdx.x, mb = blockIdx.y, g = blockIdx.z;
    const int* nodes = g ? out_nodes : in_nodes;
    int tid = threadIdx.x, wave = tid >> 6, lane = tid & 63;
    int wn = wave >> 1, wm = wave & 1;
    int r = tid >> 2, seg = (tid & 3) * 8;
    int node = nodes[mb * 64 + r];
    const float* bsrc = node_emb + (size_t)node * 512 + seg;
    const unsigned short* asrc = Wat + (size_t)(nb * 64 + r) * 512 + seg;
    f32x4 z4 = {0.f, 0.f, 0.f, 0.f};
    f32x4 acc[2][2];
#pragma unroll
    for (int a = 0; a < 2; a++)
#pragma unroll
        for (int b = 0; b < 2; b++) acc[a][b] = z4;
    for (int k0 = 0; k0 < 512; k0 += 32) {
        __syncthreads();
        *(uint4*)&At[r][seg] = *(const uint4*)(asrc + k0);
        float4 lo = *(const float4*)(bsrc + k0);
        float4 hi = *(const float4*)(bsrc + k0 + 4);
        alignas(16) unsigned short t8[8] = {
            f2b(lo.x), f2b(lo.y), f2b(lo.z), f2b(lo.w),
            f2b(hi.x), f2b(hi.y), f2b(hi.z), f2b(hi.w)};
        *(uint4*)&Bt[r][seg] = *(uint4*)t8;
        __syncthreads();
#pragma unroll
        for (int nf = 0; nf < 2; nf++) {
            bf16x8 a = *(bf16x8*)&At[wn * 32 + nf * 16 + (lane & 15)][(lane >> 4) * 8];
#pragma unroll
            for (int mf = 0; mf < 2; mf++) {
                bf16x8 b = *(bf16x8*)&Bt[wm * 32 + mf * 16 + (lane & 15)][(lane >> 4) * 8];
                acc[nf][mf] = __builtin_amdgcn_mfma_f32_16x16x32_bf16(a, b, acc[nf][mf], 0, 0, 0);
            }
        }
    }
    unsigned short* htg = ht + (size_t)g * 4 * 128 * 4096;
#pragma unroll
    for (int nf = 0; nf < 2; nf++)
#pragma unroll
        for (int mf = 0; mf < 2; mf++) {
            int i = mb * 64 + wm * 32 + mf * 16 + (lane & 15);
            int n0 = nb * 64 + wn * 32 + nf * 16 + (lane >> 4) * 4;
#pragma unroll
            for (int q = 0; q < 4; q++)
                htg[(size_t)(n0 + q) * 4096 + i] = f2b(acc[nf][mf][q]);
        }
}

// ---- f1/f2
__global__ void k_f12(const unsigned short* ht, const float* a1,
                      const float* a2, float* f1, float* f2) {
    int idx = blockIdx.x * 256 + threadIdx.x;
    int i = idx & 4095;
    int h = (idx >> 12) & 3;
    const unsigned short* p = ht + (size_t)(idx >> 12) * 128 * 4096 + i;
    float s1 = 0.f, s2 = 0.f;
    for (int d = 0; d < 128; d++) {
        float v = b2f(p[(size_t)d * 4096]);
        s1 += v * a1[h * 128 + d];
        s2 += v * a2[h * 128 + d];
    }
    f1[idx] = s1; f2[idx] = s2;
}

// ---- GAT PV, split-j x2, A-tile register prefetch
__global__ __launch_bounds__(256) void k_gat_pv_split2(
        const unsigned short* ht, const unsigned long long* bits,
        const float* f1, const float* f2, float* partO, float* partS) {
    __shared__ __align__(16) unsigned short At[128][64 + PADW];
    __shared__ __align__(16) unsigned short Pt[64][64 + PADW];
    int mb = blockIdx.x, hh = blockIdx.y, g = blockIdx.z;
    int h = hh >> 1, js = hh & 1;
    int tid = threadIdx.x, wave = tid >> 6, lane = tid & 63;
    int wn = wave >> 1, wm = wave & 1;
    const unsigned short* htp = ht + (size_t)(g * 4 + h) * 128 * 4096;
    const float* f2p = f2 + (size_t)(g * 4 + h) * 4096;
    const unsigned long long* bitp = bits + (size_t)g * 4096 * 64 + (size_t)(mb * 64) * 64;
    int iloc = tid >> 2, jc = tid & 3;
    float myf1 = f1[(size_t)(g * 4 + h) * 4096 + mb * 64 + iloc];
    float s_acc = 0.f;
    f32x4 z4 = {0.f, 0.f, 0.f, 0.f};
    f32x4 acc[4][2];
#pragma unroll
    for (int a = 0; a < 4; a++)
#pragma unroll
        for (int b = 0; b < 2; b++) acc[a][b] = z4;
    int pd = tid >> 3, psg = (tid & 7) * 8;
    uint4 apre[4];
#pragma unroll
    for (int q = 0; q < 4; q++)
        apre[q] = *(const uint4*)(htp + (size_t)(pd + q * 32) * 4096 + (js << 11) + psg);
    for (int jt = 0; jt < 32; jt++) {
        int j0 = (js << 11) + (jt << 6);
        __syncthreads();
#pragma unroll
        for (int q = 0; q < 4; q++)
            *(uint4*)&At[pd + q * 32][psg] = apre[q];
        unsigned long long w = bitp[(size_t)iloc * 64 + (j0 >> 6)] >> (jc * 16);
        float fv[16];
#pragma unroll
        for (int q = 0; q < 4; q++) {
            float4 vv = *(const float4*)(f2p + j0 + jc * 16 + q * 4);
            fv[q * 4 + 0] = vv.x; fv[q * 4 + 1] = vv.y;
            fv[q * 4 + 2] = vv.z; fv[q * 4 + 3] = vv.w;
        }
        alignas(16) unsigned short pv[16];
        float rs = 0.f;
#pragma unroll
        for (int e = 0; e < 16; e++) {
            float ee = myf1 + fv[e];
            ee = ee > 0.f ? ee : 0.2f * ee;
            float pval = ((w >> e) & 1ull) ? __expf(ee) : 0.f;
            rs += pval;
            pv[e] = f2b(pval);
        }
        rs += __shfl_xor(rs, 1);
        rs += __shfl_xor(rs, 2);
        s_acc += rs;
        *(uint4*)&Pt[iloc][jc * 16] = *(uint4*)&pv[0];
        *(uint4*)&Pt[iloc][jc * 16 + 8] = *(uint4*)&pv[8];
        __syncthreads();
        if (jt + 1 < 32) {
            int j1 = (js << 11) + ((jt + 1) << 6);
#pragma unroll
            for (int q = 0; q < 4; q++)
                apre[q] = *(const uint4*)(htp + (size_t)(pd + q * 32) * 4096 + j1 + psg);
        }
#pragma unroll
        for (int ks = 0; ks < 2; ks++) {
            bf16x8 bfr[2];
#pragma unroll
            for (int mf = 0; mf < 2; mf++)
                bfr[mf] = *(bf16x8*)&Pt[wm * 32 + mf * 16 + (lane & 15)][ks * 32 + (lane >> 4) * 8];
#pragma unroll
            for (int nf = 0; nf < 4; nf++) {
                bf16x8 a = *(bf16x8*)&At[wn * 64 + nf * 16 + (lane & 15)][ks * 32 + (lane >> 4) * 8];
#pragma unroll
                for (int mf = 0; mf < 2; mf++)
                    acc[nf][mf] = __builtin_amdgcn_mfma_f32_16x16x32_bf16(a, bfr[mf], acc[nf][mf], 0, 0, 0);
            }
        }
    }
    int slab = ((g * 4 + h) * 2 + js);
    if ((tid & 3) == 0)
        partS[(size_t)slab * 4096 + mb * 64 + iloc] = s_acc;
#pragma unroll
    for (int nf = 0; nf < 4; nf++)
#pragma unroll
        for (int mf = 0; mf < 2; mf++) {
            int il = wm * 32 + mf * 16 + (lane & 15);
            int i = mb * 64 + il;
            int d0 = wn * 64 + nf * 16 + (lane >> 4) * 4;
            float4 v;
            v.x = acc[nf][mf][0];
            v.y = acc[nf][mf][1];
            v.z = acc[nf][mf][2];
            v.w = acc[nf][mf][3];
            *(float4*)&partO[((size_t)slab * 4096 + i) * 128 + d0] = v;
        }
}

// ---- combine pv splits (x2)
__global__ void k_pv_combine(const float* partO, const float* partS, float* emb) {
    int idx = blockIdx.x * 256 + threadIdx.x;
    int d = idx & 127;
    int i = (idx >> 7) & 4095;
    int h = (idx >> 19) & 3;
    int g = idx >> 21;
    float s = 0.f, v = 0.f;
#pragma unroll
    for (int js = 0; js < 2; js++) {
        int slab = (g * 4 + h) * 2 + js;
        s += partS[(size_t)slab * 4096 + i];
        v += partO[((size_t)slab * 4096 + i) * 128 + d];
    }
    emb[((size_t)g * 4096 + i) * 512 + h * 128 + d] = s > 0.f ? v / s : 0.f;
}

// ---- GAT PV full (tier C fallback)
__global__ __launch_bounds__(256) void k_gat_pv_full(
        const unsigned short* ht, const unsigned long long* bits,
        const float* f1, const float* f2, float* emb) {
    __shared__ __align__(16) unsigned short At[128][64 + PADW];
    __shared__ __align__(16) unsigned short Pt[64][64 + PADW];
    __shared__ float s_lds[64];
    int mb = blockIdx.x, h = blockIdx.y, g = blockIdx.z;
    int tid = threadIdx.x, wave = tid >> 6, lane = tid & 63;
    int wn = wave >> 1, wm = wave & 1;
    const unsigned short* htp = ht + (size_t)(g * 4 + h) * 128 * 4096;
    const float* f2p = f2 + (size_t)(g * 4 + h) * 4096;
    const unsigned long long* bitp = bits + (size_t)g * 4096 * 64 + (size_t)(mb * 64) * 64;
    int iloc = tid >> 2, jc = tid & 3;
    float myf1 = f1[(size_t)(g * 4 + h) * 4096 + mb * 64 + iloc];
    float s_acc = 0.f;
    f32x4 z4 = {0.f, 0.f, 0.f, 0.f};
    f32x4 acc[4][2];
#pragma unroll
    for (int a = 0; a < 4; a++)
#pragma unroll
        for (int b = 0; b < 2; b++) acc[a][b] = z4;
    for (int j0 = 0; j0 < 4096; j0 += 64) {
        __syncthreads();
#pragma unroll
        for (int q = 0; q < 4; q++) {
            int c = tid + q * 256;
            int d = c >> 3, sg = (c & 7) * 8;
            *(uint4*)&At[d][sg] = *(const uint4*)(htp + (size_t)d * 4096 + j0 + sg);
        }
        unsigned long long w = bitp[(size_t)iloc * 64 + (j0 >> 6)] >> (jc * 16);
        float fv[16];
#pragma unroll
        for (int q = 0; q < 4; q++) {
            float4 vv = *(const float4*)(f2p + j0 + jc * 16 + q * 4);
            fv[q * 4 + 0] = vv.x; fv[q * 4 + 1] = vv.y;
            fv[q * 4 + 2] = vv.z; fv[q * 4 + 3] = vv.w;
        }
        alignas(16) unsigned short pv[16];
        float rs = 0.f;
#pragma unroll
        for (int e = 0; e < 16; e++) {
            float ee = myf1 + fv[e];
            ee = ee > 0.f ? ee : 0.2f * ee;
            float pval = ((w >> e) & 1ull) ? __expf(ee) : 0.f;
            rs += pval;
            pv[e] = f2b(pval);
        }
        rs += __shfl_xor(rs, 1);
        rs += __shfl_xor(rs, 2);
        s_acc += rs;
        *(uint4*)&Pt[iloc][jc * 16] = *(uint4*)&pv[0];
        *(uint4*)&Pt[iloc][jc * 16 + 8] = *(uint4*)&pv[8];
        __syncthreads();
#pragma unroll
        for (int ks = 0; ks < 2; ks++) {
            bf16x8 bfr[2];
#pragma unroll
            for (int mf = 0; mf < 2; mf++)
                bfr[mf] = *(bf16x8*)&Pt[wm * 32 + mf * 16 + (lane & 15)][ks * 32 + (lane >> 4) * 8];
#pragma unroll
            for (int nf = 0; nf < 4; nf++) {
                bf16x8 a = *(bf16x8*)&At[wn * 64 + nf * 16 + (lane & 15)][ks * 32 + (lane >> 4) * 8];
#pragma unroll
                for (int mf = 0; mf < 2; mf++)
                    acc[nf][mf] = __builtin_amdgcn_mfma_f32_16x16x32_bf16(a, bfr[mf], acc[nf][mf], 0, 0, 0);
            }
        }
    }
    if ((tid & 3) == 0) s_lds[iloc] = s_acc;
    __syncthreads();
    float* embp = emb + (size_t)g * 4096 * 512;
#pragma unroll
    for (int nf = 0; nf < 4; nf++)
#pragma unroll
        for (int mf = 0; mf < 2; mf++) {
            int il = wm * 32 + mf * 16 + (lane & 15);
            float sv = s_lds[il];
            float inv = sv > 0.f ? 1.f / sv : 0.f;
            int i = mb * 64 + il;
            int d0 = wn * 64 + nf * 16 + (lane >> 4) * 4;
            float4 v;
            v.x = acc[nf][mf][0] * inv;
            v.y = acc[nf][mf][1] * inv;
            v.z = acc[nf][mf][2] * inv;
            v.w = acc[nf][mf][3] * inv;
            *(float4*)&embp[(size_t)i * 512 + h * 128 + d0] = v;
        }
}

// ---- head/tail gather + elu
__global__ void k_headtail(const float* emb, const int* imh, const int* omh,
                           const int* imt, const int* omt, unsigned short* hcat) {
    int idx = blockIdx.x * 256 + threadIdx.x;
    if (idx >= 2 * 1024 * 512) return;
    int which = idx >> 19;
    int o = idx & 524287;
    int b = o >> 9, c = o & 511;
    int i0 = which ? imt[b] : imh[b];
    int i1 = which ? omt[b] : omh[b];
    float v = emb[(size_t)i0 * 512 + c] + emb[(size_t)(4096 + i1) * 512 + c];
    v = v > 0.f ? v : (__expf(v) - 1.f);
    hcat[(size_t)which * 1024 * 1024 + (size_t)b * 1024 + c] = f2b(v);
}

// ---- gi vocab table v2 + register-prefetch pipeline
__global__ __launch_bounds__(256) void k_gi2(
        const unsigned short* wz, const float* word_emb,
        const unsigned short* wemb16, int use16, unsigned short* giTab) {
    __shared__ __align__(16) unsigned short At[128][32 + PADW];
    __shared__ __align__(16) unsigned short Bt[128][32 + PADW];
    int b = blockIdx.x;
    int xcd = b & 7, s = b >> 3;
    int nb = s % 12;
    int wbg = xcd * 63 + s / 12;
    if (wbg >= 500) return;
    int wb = wbg >> 1, g = wbg & 1;
    const unsigned short* Wi = wz + (size_t)(g ? 2 : 0) * 786432;
    int tid = threadIdx.x, wave = tid >> 6, lane = tid & 63;
    int wn = wave >> 1, wm = wave & 1;
    int r = tid >> 1, h2 = tid & 1;
    const unsigned short* asrc = Wi + (size_t)(nb * 128 + r) * 512 + h2 * 16;
    const unsigned short* bsrc16 = wemb16 + (size_t)(wb * 128 + r) * 512 + h2 * 16;
    const float* bsrc32 = word_emb + (size_t)(wb * 128 + r) * 512 + h2 * 16;
    f32x4 z4 = {0.f, 0.f, 0.f, 0.f};
    f32x4 acc[4][4];
#pragma unroll
    for (int a = 0; a < 4; a++)
#pragma unroll
        for (int c = 0; c < 4; c++) acc[a][c] = z4;
    uint4 apre0, apre1, bpre0, bpre1;
    float4 fp0, fp1, fp2v, fp3;
    apre0 = ((const uint4*)asrc)[0];
    apre1 = *(const uint4*)(asrc + 8);
    if (use16) {
        bpre0 = ((const uint4*)bsrc16)[0];
        bpre1 = *(const uint4*)(bsrc16 + 8);
    } else {
        fp0 = ((const float4*)bsrc32)[0]; fp1 = ((const float4*)bsrc32)[1];
        fp2v = ((const float4*)bsrc32)[2]; fp3 = ((const float4*)bsrc32)[3];
    }
    for (int k0 = 0; k0 < 512; k0 += 32) {
        __syncthreads();
        *(uint4*)&At[r][h2 * 16]     = apre0;
        *(uint4*)&At[r][h2 * 16 + 8] = apre1;
        if (use16) {
            *(uint4*)&Bt[r][h2 * 16]     = bpre0;
            *(uint4*)&Bt[r][h2 * 16 + 8] = bpre1;
        } else {
            alignas(16) unsigned short t16[16] = {
                f2b(fp0.x), f2b(fp0.y), f2b(fp0.z), f2b(fp0.w),
                f2b(fp1.x), f2b(fp1.y), f2b(fp1.z), f2b(fp1.w),
                f2b(fp2v.x), f2b(fp2v.y), f2b(fp2v.z), f2b(fp2v.w),
                f2b(fp3.x), f2b(fp3.y), f2b(fp3.z), f2b(fp3.w)};
            *(uint4*)&Bt[r][h2 * 16]     = ((uint4*)t16)[0];
            *(uint4*)&Bt[r][h2 * 16 + 8] = ((uint4*)t16)[1];
        }
        __syncthreads();
        if (k0 + 32 < 512) {
            int k1 = k0 + 32;
            apre0 = *(const uint4*)(asrc + k1);
            apre1 = *(const uint4*)(asrc + k1 + 8);
            if (use16) {
                bpre0 = *(const uint4*)(bsrc16 + k1);
                bpre1 = *(const uint4*)(bsrc16 + k1 + 8);
            } else {
                fp0 = ((const float4*)(bsrc32 + k1))[0];
                fp1 = ((const float4*)(bsrc32 + k1))[1];
                fp2v = ((const float4*)(bsrc32 + k1))[2];
                fp3 = ((const float4*)(bsrc32 + k1))[3];
            }
        }
        bf16x8 av[4], bv[4];
#pragma unroll
        for (int nf = 0; nf < 4; nf++)
            av[nf] = *(bf16x8*)&At[wn * 64 + nf * 16 + (lane & 15)][(lane >> 4) * 8];
#pragma unroll
        for (int mf = 0; mf < 4; mf++)
            bv[mf] = *(bf16x8*)&Bt[wm * 64 + mf * 16 + (lane & 15)][(lane >> 4) * 8];
#pragma unroll
        for (int nf = 0; nf < 4; nf++)
#pragma unroll
            for (int mf = 0; mf < 4; mf++)
                acc[nf][mf] = __builtin_amdgcn_mfma_f32_16x16x32_bf16(av[nf], bv[mf], acc[nf][mf], 0, 0, 0);
    }
#pragma unroll
    for (int nf = 0; nf < 4; nf++)
#pragma unroll
        for (int mf = 0; mf < 4; mf++) {
            int w = wb * 128 + wm * 64 + mf * 16 + (lane & 15);
            int n0 = nb * 128 + wn * 64 + nf * 16 + (lane >> 4) * 4;
            alignas(8) unsigned short o4[4];
#pragma unroll
            for (int q = 0; q < 4; q++) o4[q] = f2b(acc[nf][mf][q]);
            *(unsigned long long*)&giTab[((size_t)g * 32000 + w) * 1536 + n0] =
                *(unsigned long long*)o4;
        }
}

// ---- R15: cooperative persistent GRU. 1024 blocks x 256 thr; block handles
//      (nb, mbase) and (nb, mbase+128). fp32 h in registers; hb ping-pong;
//      grid.sync() per step. Same math/order as k_gru_step6.
__global__ __launch_bounds__(256, 4) void k_gru_coop(
        const unsigned short* wswz, const unsigned short* giTab,
        const float* bi_in, const float* bh_in,
        const float* bi_out, const float* bh_out,
        const int* in_ctx, const int* out_ctx,
        const int* perm, const int* slen,
        unsigned short* hb0, unsigned short* hb1, float* hf) {
    cg::grid_group grid = cg::this_grid();
    int b = blockIdx.x;
    int xcd = b & 7, u = b >> 3;
    int nb = u & 7;
    int mbase = (u >> 3) * 8 + xcd;        // 0..127
    int tid = threadIdx.x, wave = tid >> 6, lane = tid & 63;
    int wn2 = wave >> 1, nf2 = wave & 1;
    int colbase = nb * 64 + wn2 * 32 + nf2 * 16 + (lane >> 4) * 4;
    __shared__ __align__(16) unsigned short Ht[32][512 + PADW];
    __shared__ int orig_s[2][32];
    __shared__ int slen_s[2][32];
    __shared__ int widx_s[32];
    int p0A = mbase * 32;
    int p0B = 4096 + mbase * 32;
    if (tid < 32) {
        orig_s[0][tid] = perm[p0A + tid]; slen_s[0][tid] = slen[p0A + tid];
        orig_s[1][tid] = perm[p0B + tid]; slen_s[1][tid] = slen[p0B + tid];
    }
    __syncthreads();
    int smaxA = slen_s[0][0], smaxB = slen_s[1][0];
    float4 hregA[2], hregB[2];
#pragma unroll
    for (int mf = 0; mf < 2; mf++) {
        hregA[mf] = make_float4(0.f, 0.f, 0.f, 0.f);
        hregB[mf] = make_float4(0.f, 0.f, 0.f, 0.f);
    }
    f32x4 z4 = {0.f, 0.f, 0.f, 0.f};
    for (int t = 0; t < 64; ++t) {
        const unsigned short* hp = (t & 1) ? hb1 : hb0;
        unsigned short* hn = (t & 1) ? hb0 : hb1;
#pragma unroll
        for (int tile = 0; tile < 2; ++tile) {
            int smax = tile ? smaxB : smaxA;
            if (t < smax) {
                int p0 = tile ? p0B : p0A;
                const int* ctx = tile ? out_ctx : in_ctx;
                __syncthreads();                       // prev tile done with Ht
                const unsigned short* hbase = hp + (size_t)p0 * 512;
#pragma unroll
                for (int j = 0; j < 8; j++) {
                    int flat = tid + j * 256;
                    int row = flat >> 6, c16 = flat & 63;
                    *(uint4*)&Ht[row][c16 * 8] =
                        *(const uint4*)(hbase + (size_t)row * 512 + c16 * 8);
                }
                if (tid < 32)
                    widx_s[tid] = ctx[orig_s[tile][tid] * 64 + t];
                __syncthreads();
                // early gathers
                const unsigned short* giG = giTab + (size_t)(tile ? 32000 : 0) * 1536;
                unsigned long long gv0[2], gv1[2], gv2[2];
                bool validf[2];
#pragma unroll
                for (int mf = 0; mf < 2; mf++) {
                    int rloc = mf * 16 + (lane & 15);
                    validf[mf] = t < slen_s[tile][rloc];
                    int w = widx_s[rloc];
                    const unsigned short* grow = giG + (size_t)w * 1536;
                    if (validf[mf]) {
                        gv0[mf] = __builtin_nontemporal_load((const unsigned long long*)(grow + colbase));
                        gv1[mf] = __builtin_nontemporal_load((const unsigned long long*)(grow + 512 + colbase));
                        gv2[mf] = __builtin_nontemporal_load((const unsigned long long*)(grow + 1024 + colbase));
                    } else {
                        gv0[mf] = 0ull; gv1[mf] = 0ull; gv2[mf] = 0ull;
                    }
                }
                const unsigned short* wf = wswz + (size_t)tile * 786432 + nb * 32768
                                           + wn2 * 16384 + nf2 * 8192 + (size_t)lane * 8;
                f32x4 acc[3][2];
#pragma unroll
                for (int a = 0; a < 3; a++)
#pragma unroll
                    for (int c = 0; c < 2; c++) acc[a][c] = z4;
#pragma unroll
                for (int kt = 0; kt < 16; kt++) {
                    bf16x8 hbv[2];
#pragma unroll
                    for (int mf = 0; mf < 2; mf++)
                        hbv[mf] = *(bf16x8*)&Ht[mf * 16 + (lane & 15)][kt * 32 + (lane >> 4) * 8];
#pragma unroll
                    for (int q = 0; q < 3; q++) {
                        bf16x8 a = *(const bf16x8*)(wf + q * 262144 + kt * 512);
#pragma unroll
                        for (int mf = 0; mf < 2; mf++)
                            acc[q][mf] = __builtin_amdgcn_mfma_f32_16x16x32_bf16(a, hbv[mf], acc[q][mf], 0, 0, 0);
                    }
                }
                const float* bi = tile ? bi_out : bi_in;
                const float* bh = tile ? bh_out : bh_in;
#pragma unroll
                for (int mf = 0; mf < 2; mf++) {
                    int rloc = mf * 16 + (lane & 15);
                    int m = p0 + rloc;
                    bool valid = validf[mf];
                    float4 hold4 = tile ? hregB[mf] : hregA[mf];
                    float ho[4] = {hold4.x, hold4.y, hold4.z, hold4.w};
                    float hv4[4];
                    alignas(8) unsigned short hb16[4];
#pragma unroll
                    for (int q = 0; q < 4; q++) {
                        int n = colbase + q;
                        float gir = b2f((unsigned short)(gv0[mf] >> (16 * q)));
                        float giz = b2f((unsigned short)(gv1[mf] >> (16 * q)));
                        float gin = b2f((unsigned short)(gv2[mf] >> (16 * q)));
                        float gr = gir + bi[n] + acc[0][mf][q] + bh[n];
                        float gz = giz + bi[512 + n] + acc[1][mf][q] + bh[512 + n];
                        float gn = gin + bi[1024 + n];
                        float ghn = acc[2][mf][q] + bh[1024 + n];
                        float rr = 1.f / (1.f + __expf(-gr));
                        float zz = 1.f / (1.f + __expf(-gz));
                        float narg = gn + rr * ghn;
                        float e2 = __expf(2.f * narg);
                        float nn = 1.f - 2.f / (e2 + 1.f);
                        float hv = valid ? ((1.f - zz) * nn + zz * ho[q]) : ho[q];
                        hv4[q] = hv;
                        hb16[q] = f2b(hv);
                    }
                    float4 nh = make_float4(hv4[0], hv4[1], hv4[2], hv4[3]);
                    if (tile) hregB[mf] = nh; else hregA[mf] = nh;
                    *(unsigned long long*)&hn[(size_t)m * 512 + colbase] =
                        *(unsigned long long*)hb16;
                }
            }
        }
        grid.sync();
    }
    // final: publish fp32 h for avgcat
#pragma unroll
    for (int mf = 0; mf < 2; mf++) {
        int mA = p0A + mf * 16 + (lane & 15);
        int mB = p0B + mf * 16 + (lane & 15);
        *(float4*)&hf[(size_t)mA * 512 + colbase] = hregA[mf];
        *(float4*)&hf[(size_t)mB * 512 + colbase] = hregB[mf];
    }
}

// ---- GRU step v6 (fallback when cooperative launch unavailable)
__global__ __launch_bounds__(256) void k_gru_step6(
        const unsigned short* wswz, const unsigned short* giTab,
        const float* bi_in, const float* bh_in,
        const float* bi_out, const float* bh_out,
        const int* in_ctx, const int* out_ctx,
        const int* perm, const int* slen,
        const unsigned short* hb_prev, unsigned short* hb_next, float* hf,
        int t) {
    int b = blockIdx.x;
    int xcd = b & 7, s = b >> 3;
    int nb = s & 7;
    int mb = (s >> 3) * 8 + xcd;
    int p0 = mb * 32;
    if (t >= slen[p0]) return;
    __shared__ __align__(16) unsigned short Ht[32][512 + PADW];
    __shared__ int widx_s[32];
    __shared__ int slen_s[32];
    int tid = threadIdx.x, wave = tid >> 6, lane = tid & 63;
    int wn2 = wave >> 1, nf2 = wave & 1;
    int gsel = mb >= 128;
    const int* ctx = gsel ? out_ctx : in_ctx;
    if (tid < 32) {
        int p = p0 + tid;
        int orig = perm[p];
        widx_s[tid] = ctx[orig * 64 + t];
        slen_s[tid] = slen[p];
    }
    const unsigned short* hbase = hb_prev + (size_t)p0 * 512;
#pragma unroll
    for (int j = 0; j < 8; j++) {
        int flat = tid + j * 256;
        int row = flat >> 6, c16 = flat & 63;
        *(uint4*)&Ht[row][c16 * 8] = *(const uint4*)(hbase + (size_t)row * 512 + c16 * 8);
    }
    __syncthreads();
    const unsigned short* giG = giTab + (size_t)(gsel ? 32000 : 0) * 1536;
    int colbase = nb * 64 + wn2 * 32 + nf2 * 16 + (lane >> 4) * 4;
    unsigned long long gv0[2], gv1[2], gv2[2];
    float4 hold[2];
    bool validf[2];
#pragma unroll
    for (int mf = 0; mf < 2; mf++) {
        int rloc = mf * 16 + (lane & 15);
        validf[mf] = t < slen_s[rloc];
        int w = widx_s[rloc];
        const unsigned short* grow = giG + (size_t)w * 1536;
        hold[mf] = *(const float4*)&hf[(size_t)(p0 + rloc) * 512 + colbase];
        if (validf[mf]) {
            gv0[mf] = __builtin_nontemporal_load((const unsigned long long*)(grow + colbase));
            gv1[mf] = __builtin_nontemporal_load((const unsigned long long*)(grow + 512 + colbase));
            gv2[mf] = __builtin_nontemporal_load((const unsigned long long*)(grow + 1024 + colbase));
        } else {
            gv0[mf] = 0ull; gv1[mf] = 0ull; gv2[mf] = 0ull;
        }
    }
    const unsigned short* wf = wswz + (size_t)gsel * 786432 + nb * 32768
                               + wn2 * 16384 + nf2 * 8192 + (size_t)lane * 8;
    f32x4 z4 = {0.f, 0.f, 0.f, 0.f};
    f32x4 acc[3][2];
#pragma unroll
    for (int a = 0; a < 3; a++)
#pragma unroll
        for (int c = 0; c < 2; c++) acc[a][c] = z4;
#pragma unroll
    for (int kt = 0; kt < 16; kt++) {
        bf16x8 hbv[2];
#pragma unroll
        for (int mf = 0; mf < 2; mf++)
            hbv[mf] = *(bf16x8*)&Ht[mf * 16 + (lane & 15)][kt * 32 + (lane >> 4) * 8];
#pragma unroll
        for (int q = 0; q < 3; q++) {
            bf16x8 a = *(const bf16x8*)(wf + q * 262144 + kt * 512);
#pragma unroll
            for (int mf = 0; mf < 2; mf++)
                acc[q][mf] = __builtin_amdgcn_mfma_f32_16x16x32_bf16(a, hbv[mf], acc[q][mf], 0, 0, 0);
        }
    }
    const float* bi = gsel ? bi_out : bi_in;
    const float* bh = gsel ? bh_out : bh_in;
#pragma unroll
    for (int mf = 0; mf < 2; mf++) {
        int rloc = mf * 16 + (lane & 15);
        int m = p0 + rloc;
        bool valid = validf[mf];
        float ho[4] = {hold[mf].x, hold[mf].y, hold[mf].z, hold[mf].w};
        float hn[4];
        alignas(8) unsigned short hb16[4];
#pragma unroll
        for (int q = 0; q < 4; q++) {
            int n = colbase + q;
            float gir = b2f((unsigned short)(gv0[mf] >> (16 * q)));
            float giz = b2f((unsigned short)(gv1[mf] >> (16 * q)));
            float gin = b2f((unsigned short)(gv2[mf] >> (16 * q)));
            float gr = gir + bi[n] + acc[0][mf][q] + bh[n];
            float gz = giz + bi[512 + n] + acc[1][mf][q] + bh[512 + n];
            float gn = gin + bi[1024 + n];
            float ghn = acc[2][mf][q] + bh[1024 + n];
            float rr = 1.f / (1.f + __expf(-gr));
            float zz = 1.f / (1.f + __expf(-gz));
            float narg = gn + rr * ghn;
            float e2 = __expf(2.f * narg);
            float nn = 1.f - 2.f / (e2 + 1.f);
            float hv = valid ? ((1.f - zz) * nn + zz * ho[q]) : ho[q];
            hn[q] = hv;
            hb16[q] = f2b(hv);
        }
        if (valid)
            *(float4*)&hf[(size_t)m * 512 + colbase] = make_float4(hn[0], hn[1], hn[2], hn[3]);
        *(unsigned long long*)&hb_next[(size_t)m * 512 + colbase] = *(unsigned long long*)hb16;
    }
}

// ---- GRU step fused (tier C fallback)
__global__ __launch_bounds__(256) void k_gru_step_fused(
        const unsigned short* wz,
        const float* bi_in, const float* bh_in,
        const float* bi_out, const float* bh_out,
        const int* in_ctx, const int* out_ctx,
        const int* in_len, const int* out_len,
        const float* word_emb,
        const unsigned short* hb_prev, unsigned short* hb_next, float* hf,
        int t) {
    __shared__ __align__(16) unsigned short Wt[6][64][32 + PADW];
    __shared__ __align__(16) unsigned short Xt[64][32 + PADW];
    __shared__ __align__(16) unsigned short Ht[64][32 + PADW];
    int nb = blockIdx.x, mb = blockIdx.y;
    int tid = threadIdx.x, wave = tid >> 6, lane = tid & 63;
    int wn = wave >> 1, wm = wave & 1;
    int gsel = mb >= 64;
    const unsigned short* Wi = wz + (size_t)(gsel ? 2 : 0) * 786432;
    const unsigned short* Wh = wz + (size_t)(gsel ? 3 : 1) * 786432;
    const int* ctx = gsel ? out_ctx : in_ctx;
    int r = tid >> 2, seg = (tid & 3) * 8;
    int mrow = mb * 64 + r;
    int lrow = mrow - (gsel ? 4096 : 0);
    int widx = ctx[lrow * 64 + t];
    const float* xsrc = word_emb + (size_t)widx * 512 + seg;
    const unsigned short* hsrc = hb_prev + (size_t)mrow * 512 + seg;
    f32x4 z4 = {0.f, 0.f, 0.f, 0.f};
    f32x4 acc[6][2][2];
#pragma unroll
    for (int a = 0; a < 6; a++)
#pragma unroll
        for (int b = 0; b < 2; b++)
#pragma unroll
            for (int c = 0; c < 2; c++) acc[a][b][c] = z4;
    for (int k0 = 0; k0 < 512; k0 += 32) {
        __syncthreads();
#pragma unroll
        for (int q = 0; q < 6; q++) {
            const unsigned short* base = (q < 3) ? Wi : Wh;
            int gg = (q < 3) ? q : q - 3;
            *(uint4*)&Wt[q][r][seg] =
                *(const uint4*)(base + (size_t)(gg * 512 + nb * 64 + r) * 512 + k0 + seg);
        }
        float4 xlo = *(const float4*)(xsrc + k0);
        float4 xhi = *(const float4*)(xsrc + k0 + 4);
        alignas(16) unsigned short x8[8] = {
            f2b(xlo.x), f2b(xlo.y), f2b(xlo.z), f2b(xlo.w),
            f2b(xhi.x), f2b(xhi.y), f2b(xhi.z), f2b(xhi.w)};
        *(uint4*)&Xt[r][seg] = *(uint4*)x8;
        *(uint4*)&Ht[r][seg] = *(const uint4*)(hsrc + k0);
        __syncthreads();
        bf16x8 xb[2], hbv[2];
#pragma unroll
        for (int mf = 0; mf < 2; mf++) {
            xb[mf] = *(bf16x8*)&Xt[wm * 32 + mf * 16 + (lane & 15)][(lane >> 4) * 8];
            hbv[mf] = *(bf16x8*)&Ht[wm * 32 + mf * 16 + (lane & 15)][(lane >> 4) * 8];
        }
#pragma unroll
        for (int q = 0; q < 3; q++) {
#pragma unroll
            for (int nf = 0; nf < 2; nf++) {
                bf16x8 ai = *(bf16x8*)&Wt[q][wn * 32 + nf * 16 + (lane & 15)][(lane >> 4) * 8];
                bf16x8 ah = *(bf16x8*)&Wt[q + 3][wn * 32 + nf * 16 + (lane & 15)][(lane >> 4) * 8];
#pragma unroll
                for (int mf = 0; mf < 2; mf++) {
                    acc[q][nf][mf] = __builtin_amdgcn_mfma_f32_16x16x32_bf16(ai, xb[mf], acc[q][nf][mf], 0, 0, 0);
                    acc[q + 3][nf][mf] = __builtin_amdgcn_mfma_f32_16x16x32_bf16(ah, hbv[mf], acc[q + 3][nf][mf], 0, 0, 0);
                }
            }
        }
    }
    const float* bi = gsel ? bi_out : bi_in;
    const float* bh = gsel ? bh_out : bh_in;
    const int* len = gsel ? out_len : in_len;
#pragma unroll
    for (int nf = 0; nf < 2; nf++)
#pragma unroll
        for (int mf = 0; mf < 2; mf++) {
            int m = mb * 64 + wm * 32 + mf * 16 + (lane & 15);
            int lm = m - (gsel ? 4096 : 0);
            int n0 = nb * 64 + wn * 32 + nf * 16 + (lane >> 4) * 4;
            bool valid = t < len[lm];
            float4 hold4 = *(const float4*)&hf[(size_t)m * 512 + n0];
            float ho[4] = {hold4.x, hold4.y, hold4.z, hold4.w};
            float hn[4];
            alignas(8) unsigned short hb16[4];
#pragma unroll
            for (int q = 0; q < 4; q++) {
                int n = n0 + q;
                float gr = acc[0][nf][mf][q] + bi[n] + acc[3][nf][mf][q] + bh[n];
                float gz = acc[1][nf][mf][q] + bi[512 + n] + acc[4][nf][mf][q] + bh[512 + n];
                float gn = acc[2][nf][mf][q] + bi[1024 + n];
                float ghn = acc[5][nf][mf][q] + bh[1024 + n];
                float rr = 1.f / (1.f + __expf(-gr));
                float zz = 1.f / (1.f + __expf(-gz));
                float narg = gn + rr * ghn;
                float e2 = __expf(2.f * narg);
                float nn = 1.f - 2.f / (e2 + 1.f);
                float hv = valid ? ((1.f - zz) * nn + zz * ho[q]) : ho[q];
                hn[q] = hv;
                hb16[q] = f2b(hv);
            }
            *(float4*)&hf[(size_t)m * 512 + n0] = make_float4(hn[0], hn[1], hn[2], hn[3]);
            *(unsigned long long*)&hb_next[(size_t)m * 512 + n0] = *(unsigned long long*)hb16;
        }
}

// ---- ctx average (permuted via ipos)
__global__ void k_avgcat2(const float* hf, const int* ipos, unsigned short* hcat) {
    int idx = blockIdx.x * 256 + threadIdx.x;
    if (idx >= 1024 * 512) return;
    int b = idx >> 9, c = idx & 511;
    float si = 0.f, so = 0.f;
#pragma unroll
    for (int cc = 0; cc < 4; cc++) {
        si += hf[(size_t)ipos[b * 4 + cc] * 512 + c];
        so += hf[(size_t)ipos[4096 + b * 4 + cc] * 512 + c];
    }
    hcat[(size_t)b * 1024 + 512 + c] = f2b(so * 0.25f);
    hcat[(size_t)1024 * 1024 + (size_t)b * 1024 + 512 + c] = f2b(si * 0.25f);
}

// ---- ctx average plain (tier C)
__global__ void k_avgcat(const float* hf, unsigned short* hcat) {
    int idx = blockIdx.x * 256 + threadIdx.x;
    if (idx >= 1024 * 512) return;
    int b = idx >> 9, c = idx & 511;
    float si = 0.f, so = 0.f;
#pragma unroll
    for (int cc = 0; cc < 4; cc++) {
        si += hf[(size_t)(b * 4 + cc) * 512 + c];
        so += hf[(size_t)(4096 + b * 4 + cc) * 512 + c];
    }
    hcat[(size_t)b * 1024 + 512 + c] = f2b(so * 0.25f);
    hcat[(size_t)1024 * 1024 + (size_t)b * 1024 + 512 + c] = f2b(si * 0.25f);
}

// ---- final heads
__global__ __launch_bounds__(256) void k_final(
        const unsigned short* lgT, const unsigned short* hcat,
        const float* link_b, const float* gen_b, float* out) {
    __shared__ __align__(16) unsigned short At[64][32 + PADW];
    __shared__ __align__(16) unsigned short Bt[64][32 + PADW];
    int nb = blockIdx.x, mb = blockIdx.y, z = blockIdx.z;
    int wsel = z >> 1, asel = z & 1;
    const unsigned short* W = lgT + (size_t)wsel * 512 * 1024;
    const unsigned short* A = hcat + (size_t)asel * 1024 * 1024;
    const float* bias = wsel ? gen_b : link_b;
    int tid = threadIdx.x, wave = tid >> 6, lane = tid & 63;
    int wn = wave >> 1, wm = wave & 1;
    int r = tid >> 2, seg = (tid & 3) * 8;
    f32x4 z4 = {0.f, 0.f, 0.f, 0.f};
    f32x4 acc[2][2];
#pragma unroll
    for (int a = 0; a < 2; a++)
#pragma unroll
        for (int b = 0; b < 2; b++) acc[a][b] = z4;
    for (int k0 = 0; k0 < 1024; k0 += 32) {
        __syncthreads();
        *(uint4*)&At[r][seg] = *(const uint4*)(W + (size_t)(nb * 64 + r) * 1024 + k0 + seg);
        *(uint4*)&Bt[r][seg] = *(const uint4*)(A + (size_t)(mb * 64 + r) * 1024 + k0 + seg);
        __syncthreads();
#pragma unroll
        for (int nf = 0; nf < 2; nf++) {
            bf16x8 a = *(bf16x8*)&At[wn * 32 + nf * 16 + (lane & 15)][(lane >> 4) * 8];
#pragma unroll
            for (int mf = 0; mf < 2; mf++) {
                bf16x8 b = *(bf16x8*)&Bt[wm * 32 + mf * 16 + (lane & 15)][(lane >> 4) * 8];
                acc[nf][mf] = __builtin_amdgcn_mfma_f32_16x16x32_bf16(a, b, acc[nf][mf], 0, 0, 0);
            }
        }
    }
#pragma unroll
    for (int nf = 0; nf < 2; nf++)
#pragma unroll
        for (int mf = 0; mf < 2; mf++) {
            int m = mb * 64 + wm * 32 + mf * 16 + (lane & 15);
            int n0 = nb * 64 + wn * 32 + nf * 16 + (lane >> 4) * 4;
            float4 v;
            v.x = acc[nf][mf][0] + bias[n0 + 0];
            v.y = acc[nf][mf][1] + bias[n0 + 1];
            v.z = acc[nf][mf][2] + bias[n0 + 2];
            v.w = acc[nf][mf][3] + bias[n0 + 3];
            *(float4*)&out[(size_t)z * 524288 + (size_t)m * 512 + n0] = v;
        }
}

extern "C" void kernel_launch(void* const* d_in, const int* in_sizes, int n_in,
                              void* d_out, int out_size, void* d_ws, size_t ws_size,
                              hipStream_t stream) {
    const int* in_nodes   = (const int*)d_in[0];
    const int* out_nodes  = (const int*)d_in[1];
    const int* inner_adj  = (const int*)d_in[2];
    const int* outer_adj  = (const int*)d_in[3];
    const int* in_map_hs  = (const int*)d_in[4];
    const int* in_map_ts  = (const int*)d_in[5];
    const int* out_map_hs = (const int*)d_in[6];
    const int* out_map_ts = (const int*)d_in[7];
    const int* in_ctx     = (const int*)d_in[8];
    const int* in_len     = (const int*)d_in[9];
    const int* out_ctx    = (const int*)d_in[10];
    const int* out_len    = (const int*)d_in[11];
    const float* node_emb = (const float*)d_in[14];
    const float* word_emb = (const float*)d_in[15];
    const float* W_att    = (const float*)d_in[16];
    const float* a1       = (const float*)d_in[17];
    const float* a2       = (const float*)d_in[18];
    const float* gi_Wi    = (const float*)d_in[19];
    const float* gi_Wh    = (const float*)d_in[20];
    const float* gi_bi    = (const float*)d_in[21];
    const float* gi_bh    = (const float*)d_in[22];
    const float* go_Wi    = (const float*)d_in[23];
    const float* go_Wh    = (const float*)d_in[24];
    const float* go_bi    = (const float*)d_in[25];
    const float* go_bh    = (const float*)d_in[26];
    const float* link_W   = (const float*)d_in[27];
    const float* link_b   = (const float*)d_in[28];
    const float* gen_W    = (const float*)d_in[29];
    const float* gen_b    = (const float*)d_in[30];

    char* p = (char*)d_ws;
    auto alloc = [&](size_t bytes) {
        char* r = p;
        p += (bytes + 255) & ~(size_t)255;
        return r;
    };
    unsigned short*      Wat  = (unsigned short*)alloc((size_t)512 * 512 * 2);
    unsigned short*      lgT  = (unsigned short*)alloc((size_t)2 * 512 * 1024 * 2);
    unsigned short*      wz   = (unsigned short*)alloc((size_t)4 * 786432 * 2);
    unsigned long long*  bits = (unsigned long long*)alloc((size_t)2 * 4096 * 64 * 8);
    unsigned short*      ht   = (unsigned short*)alloc((size_t)2 * 4 * 128 * 4096 * 2);
    float*               f1   = (float*)alloc((size_t)2 * 4 * 4096 * 4);
    float*               f2   = (float*)alloc((size_t)2 * 4 * 4096 * 4);
    float*               emb  = (float*)alloc((size_t)2 * 4096 * 512 * 4);
    float*               hf   = (float*)alloc((size_t)8192 * 512 * 4);
    unsigned short*      hb   = (unsigned short*)alloc((size_t)2 * 8192 * 512 * 2);
    unsigned short*      hcat = (unsigned short*)alloc((size_t)2 * 1024 * 1024 * 2);
    size_t need_base = (size_t)(p - (char*)d_ws);
    unsigned short*      wswz = (unsigned short*)alloc((size_t)2 * 786432 * 2);
    unsigned short*      giTab = (unsigned short*)alloc((size_t)2 * 32000 * 1536 * 2);
    size_t need_main = (size_t)(p - (char*)d_ws);
    unsigned short*      wemb16 = (unsigned short*)alloc((size_t)32000 * 512 * 2);
    size_t need_tierA = (size_t)(p - (char*)d_ws);
    // pv partials alias giTab (pv runs before k_gi2); 16 slabs x 4096 x 128 f32
    float* partO = (float*)giTab;
    float* partS = (float*)((char*)giTab + (size_t)16 * 4096 * 128 * 4);
    // sort arrays alias bits (bits dead after pv_split)
    int* perm = (int*)bits;
    int* slen = perm + 8192;
    int* ipos = slen + 8192;

    bool tierA = ws_size >= need_tierA;
    bool tierB = ws_size >= need_main;
    if (!tierB && ws_size < need_base) return;  // workspace too small

    k_prep_wat<<<1024, 256, 0, stream>>>(W_att, Wat);
    k_prep_lg<<<4096, 256, 0, stream>>>(link_W, gen_W, lgT);
    k_prep_gruw<<<12288, 256, 0, stream>>>(gi_Wi, gi_Wh, go_Wi, go_Wh, wz);
    k_bitpack<<<2048, 256, 0, stream>>>(inner_adj, outer_adj, bits);
    k_zero<<<16384, 256, 0, stream>>>(hf, hb);
    k_gat_h<<<dim3(8, 64, 2), 256, 0, stream>>>(Wat, node_emb, in_nodes, out_nodes, ht);
    k_f12<<<128, 256, 0, stream>>>(ht, a1, a2, f1, f2);

    if (tierB) {
        k_prep_whfrag<<<6144, 256, 0, stream>>>(gi_Wh, go_Wh, wswz);
        if (tierA) k_prep_wemb<<<8000, 256, 0, stream>>>(word_emb, wemb16);
        k_gat_pv_split2<<<dim3(64, 8, 2), 256, 0, stream>>>(ht, bits, f1, f2, partO, partS);
        k_pv_combine<<<16384, 256, 0, stream>>>(partO, partS, emb);
        k_sort<<<128, 64, 0, stream>>>(in_len, out_len, perm, slen, ipos);
        k_gi2<<<6048, 256, 0, stream>>>(wz, word_emb,
                                        tierA ? wemb16 : (const unsigned short*)nullptr,
                                        tierA ? 1 : 0, giTab);
        k_headtail<<<4096, 256, 0, stream>>>(emb, in_map_hs, out_map_hs, in_map_ts, out_map_ts, hcat);

        // ---- cooperative persistent GRU (fallback: 64x step6)
        unsigned short* hb0p = hb;
        unsigned short* hb1p = hb + (size_t)8192 * 512;
        int maxb = 0;
        hipError_t oe = hipOccupancyMaxActiveBlocksPerMultiprocessor(
            &maxb, (const void*)k_gru_coop, 256, 0);
        bool coop = (oe == hipSuccess && maxb >= 4);
        if (coop) {
            const unsigned short* wswz_c = wswz;
            const unsigned short* giTab_c = giTab;
            const int* perm_c = perm;
            const int* slen_c = slen;
            void* kargs[] = {
                (void*)&wswz_c, (void*)&giTab_c,
                (void*)&gi_bi, (void*)&gi_bh, (void*)&go_bi, (void*)&go_bh,
                (void*)&in_ctx, (void*)&out_ctx,
                (void*)&perm_c, (void*)&slen_c,
                (void*)&hb0p, (void*)&hb1p, (void*)&hf};
            hipError_t le = hipLaunchCooperativeKernel(
                (const void*)k_gru_coop, dim3(1024), dim3(256), kargs, 0, stream);
            if (le != hipSuccess) coop = false;
        }
        if (!coop) {
            for (int t = 0; t < 64; t++) {
                const unsigned short* hp = hb + (size_t)(t & 1) * 8192 * 512;
                unsigned short* hn = hb + (size_t)((t & 1) ^ 1) * 8192 * 512;
                k_gru_step6<<<2048, 256, 0, stream>>>(
                    wswz, giTab, gi_bi, gi_bh, go_bi, go_bh,
                    in_ctx, out_ctx, perm, slen, hp, hn, hf, t);
            }
        }
        k_avgcat2<<<2048, 256, 0, stream>>>(hf, ipos, hcat);
    } else {
        k_gat_pv_full<<<dim3(64, 4, 2), 256, 0, stream>>>(ht, bits, f1, f2, emb);
        k_headtail<<<4096, 256, 0, stream>>>(emb, in_map_hs, out_map_hs, in_map_ts, out_map_ts, hcat);
        for (int t = 0; t < 64; t++) {
            const unsigned short* hp = hb + (size_t)(t & 1) * 8192 * 512;
            unsigned short* hn = hb + (size_t)((t & 1) ^ 1) * 8192 * 512;
            k_gru_step_fused<<<dim3(8, 128), 256, 0, stream>>>(
                wz, gi_bi, gi_bh, go_bi, go_bh,
                in_ctx, out_ctx, in_len, out_len, word_emb, hp, hn, hf, t);
        }
        k_avgcat<<<2048, 256, 0, stream>>>(hf, hcat);
    }
    k_final<<<dim3(8, 16, 4), 256, 0, stream>>>(lgT, hcat, link_b, gen_b,
                                                (float*)d_out);
}